// Round 12
// baseline (2645.385 us; speedup 1.0000x reference)
//
#include <hip/hip_runtime.h>
#include <cstdint>
#include <cstddef>

typedef __attribute__((ext_vector_type(8))) _Float16 half8;
typedef __attribute__((ext_vector_type(4))) float f32x4;

__device__ __forceinline__ float fexp(float x){ return __expf(x); }
__device__ __forceinline__ float sig_fast(float x){
  return __builtin_amdgcn_rcpf(1.f + __expf(-x));
}
__device__ __forceinline__ float tanh_fast(float x){
  return 2.f*__builtin_amdgcn_rcpf(1.f + __expf(-2.f*x)) - 1.f;
}
__device__ __forceinline__ float sigf(float x){ return 1.0f/(1.0f+expf(-x)); }

__device__ __forceinline__ void async_lds16(const _Float16* g, _Float16* l){
  __builtin_amdgcn_global_load_lds(
      (const __attribute__((address_space(1))) void*)g,
      (__attribute__((address_space(3))) void*)l, 16, 0, 0);
}

__global__ __launch_bounds__(64)
void k_sentinel(float* out, int n){ int i=threadIdx.x; if(i<n) out[i]=1.0e9f; }

// unified embeddings: rows 0..25599 = contents, 25600..26599 = question, rest zero
__global__ __launch_bounds__(256)
void k_embed16u(const int* __restrict__ c_tok, const int* __restrict__ q_tok,
                const float* __restrict__ ef, const float* __restrict__ ed,
                _Float16* __restrict__ oh, _Float16* __restrict__ ol, int Kpad)
{
  int t = blockIdx.x; int e = threadIdx.x;
  if (e >= Kpad) return;
  _Float16 h = (_Float16)0.f, l = (_Float16)0.f;
  int tok = -1;
  if (t < 25600) tok = c_tok[t];
  else if (t < 26600) tok = q_tok[t - 25600];
  if (tok >= 0 && e < 200){
    long r = (long)tok*200 + e;
    float v = ef[r] + ed[r];
    h = (_Float16)v; l = (_Float16)(v - (float)h);
  }
  oh[(long)t*Kpad + e] = h;
  ol[(long)t*Kpad + e] = l;
}

// W[2][K][512] -> Wt_h/Wt_l[(dir*512+n)][Kpad]
__global__ __launch_bounds__(256)
void k_wsplit(const float* __restrict__ W, _Float16* __restrict__ th,
              _Float16* __restrict__ tl, int K, int Kpad)
{
  int n = blockIdx.x;               // 0..1023
  int dir = n >> 9, col = n & 511;
  for (int k = threadIdx.x; k < Kpad; k += 256){
    _Float16 h = (_Float16)0.f, l = (_Float16)0.f;
    if (k < K){
      float v = W[((long)dir*K + k)*512 + col];
      h = (_Float16)v; l = (_Float16)(v - (float)h);
    }
    th[(long)n*Kpad + k] = h;
    tl[(long)n*Kpad + k] = l;
  }
}

// ---------------- split-fp16 MFMA GEMM, z-batched, 2 or 3 passes ------------
#define MFMA16(a,b,c) __builtin_amdgcn_mfma_f32_16x16x32_f16(a,b,c,0,0,0)

__global__ __launch_bounds__(256, 2)
void k_mfma(const _Float16* __restrict__ Ahb, const _Float16* __restrict__ Alb,
            const _Float16* __restrict__ Bhb, const _Float16* __restrict__ Blb,
            float* __restrict__ Cb, int M, int K, int N, int ldc,
            long sA, long sB, long sC, int divA, int divB, int passes)
{
  const int z = blockIdx.z;
  const _Float16* Ah = Ahb + (long)(z/divA)*sA;
  const _Float16* Al = Alb + (long)(z/divA)*sA;
  const _Float16* Bh = Bhb + (long)(z/divB)*sB;
  const _Float16* Bl = Blb + (long)(z/divB)*sB;
  float* C = Cb + (long)z*sC;

  const int m0 = blockIdx.x*128, n0 = blockIdx.y*128;
  const int tid = threadIdx.x;
  const int lane = tid & 63, wave = tid >> 6;
  const int wm = wave >> 1, wn = wave & 1;     // 2x2 waves, 64x64 per wave

  __shared__ _Float16 lds[2][2048*8];

  f32x4 acc[4][4] = {};

  const int KT = K >> 5;
  const bool p3 = (passes == 3);

  auto STAGE = [&](int buf, int kt){
    const int k0 = kt*32;
    #pragma unroll
    for (int it = 0; it < 8; ++it){
      const int c  = it*256 + tid;
      const int op = it >> 1;
      const int kb = (c >> 7) & 3;
      const int row = c & 127;
      const _Float16* base = (op==0) ? Ah : (op==1) ? Al : (op==2) ? Bh : Bl;
      int gr = (op < 2) ? (m0 + row) : (n0 + row);
      if (op < 2 && gr >= M) gr = M - 1;
      const _Float16* src = base + (long)gr*K + k0 + kb*8;
      _Float16* dst = &lds[buf][(size_t)(it*256 + (tid & ~63))*8];
      async_lds16(src, dst);
    }
  };

  auto COMPUTE = [&](int buf){
    const int kb = lane >> 4, r = lane & 15;
    half8 ah[4], al[4], bh[4], bl[4];
    #pragma unroll
    for (int mi = 0; mi < 4; ++mi){
      ah[mi] = *(const half8*)&lds[buf][(size_t)(        kb*128 + wm*64 + mi*16 + r)*8];
      al[mi] = *(const half8*)&lds[buf][(size_t)( 512 + kb*128 + wm*64 + mi*16 + r)*8];
    }
    #pragma unroll
    for (int ni = 0; ni < 4; ++ni){
      bh[ni] = *(const half8*)&lds[buf][(size_t)(1024 + kb*128 + wn*64 + ni*16 + r)*8];
      bl[ni] = *(const half8*)&lds[buf][(size_t)(1536 + kb*128 + wn*64 + ni*16 + r)*8];
    }
    #pragma unroll
    for (int mi = 0; mi < 4; ++mi)
      #pragma unroll
      for (int ni = 0; ni < 4; ++ni){
        acc[mi][ni] = MFMA16(ah[mi], bh[ni], acc[mi][ni]);
        acc[mi][ni] = MFMA16(ah[mi], bl[ni], acc[mi][ni]);
        if (p3) acc[mi][ni] = MFMA16(al[mi], bh[ni], acc[mi][ni]);
      }
  };

  STAGE(0, 0);
  for (int kt = 0; kt < KT; ++kt){
    __syncthreads();
    if (kt + 1 < KT) STAGE((kt+1)&1, kt+1);
    COMPUTE(kt&1);
  }

  const int r4 = (lane >> 4) * 4, cN = lane & 15;
  #pragma unroll
  for (int mi = 0; mi < 4; ++mi)
    #pragma unroll
    for (int ni = 0; ni < 4; ++ni){
      const int row = m0 + wm*64 + mi*16 + r4;
      const int col = n0 + wn*64 + ni*16 + cN;
      #pragma unroll
      for (int r = 0; r < 4; ++r)
        if (row + r < M) C[(long)(row + r)*ldc + col] = acc[mi][ni][r];
    }
}

// ---------------- MFMA LSTM scan: 16 sequences per block ---------------------
// Recurrent matvec H[16,128] @ Wh[128,512] per step via 16x16x32 f16 MFMA,
// 3-pass split-fp16 (same verified fragment layout as k_mfma). Weights are
// per-wave register fragments (or compiler-remat from global — cheap at ~16-28
// blocks, unlike the 220-block L2-bound scalar scan: R5-R10 post-mortems).
// 8 waves, wave w owns gate-cols [w*64, w*64+64). Threads 0-511 then update
// 16x128 cell states (4 per thread) and write h back as A-fragments.
__global__ __launch_bounds__(512, 1)
void k_lstm_mf(const float* __restrict__ xg0, const _Float16* __restrict__ W0h,
               const _Float16* __restrict__ W0l, const float* __restrict__ bs0,
               float* __restrict__ out0, int P0, int S0, int T0,
               const float* __restrict__ xg1, const _Float16* __restrict__ W1h,
               const _Float16* __restrict__ W1l, const float* __restrict__ bs1,
               float* __restrict__ out1, int S1, int T1)
{
  const int bx = blockIdx.x, dir = blockIdx.y;
  const float* xg; const _Float16 *Wth, *Wtl; const float* bsb; float* out;
  int T, S, ch;
  if (bx < P0){ ch = bx;      xg = xg0; Wth = W0h; Wtl = W0l; bsb = bs0; out = out0; T = T0; S = S0; }
  else        { ch = bx - P0; xg = xg1; Wth = W1h; Wtl = W1l; bsb = bs1; out = out1; T = T1; S = S1; }
  const int sbase = ch*16;
  const int ns = (S - sbase < 16) ? (S - sbase) : 16;
  const int tid = threadIdx.x, lane = tid & 63, wv = tid >> 6;
  const int dirOff = dir*128;

  // A fragments: [kidx 0..15][row 0..15][8 halves]
  __shared__ _Float16 Ah[2048], Al[2048];
  __shared__ float gat[16*512];

  // B fragments: wave wv owns cols wv*64 + nt*16 + (lane&15), k = kt*32 + (lane>>4)*8
  const _Float16* WH = Wth + (long)dir*512*128;
  const _Float16* WL = Wtl + (long)dir*512*128;
  half8 Bh[4][4], Bl[4][4];
  #pragma unroll
  for (int nt = 0; nt < 4; ++nt)
    #pragma unroll
    for (int kt = 0; kt < 4; ++kt){
      long a = (long)(wv*64 + nt*16 + (lane & 15))*128 + kt*32 + (lane >> 4)*8;
      Bh[nt][kt] = *(const half8*)&WH[a];
      Bl[nt][kt] = *(const half8*)&WL[a];
    }

  // update-thread constants: hidden col k, seq rows srow+4i
  const int k = tid & 127;
  const int srow = tid >> 7;          // 0..3
  float bv[4];
  #pragma unroll
  for (int g = 0; g < 4; ++g) bv[g] = bsb[dir*512 + g*128 + k];
  float c[4] = {0.f, 0.f, 0.f, 0.f};
  int sg[4];
  #pragma unroll
  for (int i = 0; i < 4; ++i){
    int s = srow + 4*i;
    sg[i] = sbase + (s < ns ? s : ns - 1);
  }

  for (int i = tid; i < 2048; i += 512){ Ah[i] = (_Float16)0.f; Al[i] = (_Float16)0.f; }
  __syncthreads();

  const int t0 = dir ? T-1 : 0;
  float xc[4][4];
  #pragma unroll
  for (int i = 0; i < 4; ++i)
    #pragma unroll
    for (int g = 0; g < 4; ++g)
      xc[i][g] = xg[((long)sg[i]*T + t0)*1024 + dir*512 + g*128 + k];

  for (int tt = 0; tt < T; ++tt){
    const int t = dir ? T-1-tt : tt;
    float xn[4][4] = {};
    if (tt + 1 < T){
      const int tn = dir ? T-2-tt : tt+1;
      #pragma unroll
      for (int i = 0; i < 4; ++i)
        #pragma unroll
        for (int g = 0; g < 4; ++g)
          xn[i][g] = xg[((long)sg[i]*T + tn)*1024 + dir*512 + g*128 + k];
    }
    // matvec: acc[nt] = H @ Wh for this wave's 64 cols
    f32x4 acc[4] = {};
    #pragma unroll
    for (int kt = 0; kt < 4; ++kt){
      half8 a_h = *(const half8*)&Ah[((kt*4 + (lane >> 4))*16 + (lane & 15))*8];
      half8 a_l = *(const half8*)&Al[((kt*4 + (lane >> 4))*16 + (lane & 15))*8];
      #pragma unroll
      for (int nt = 0; nt < 4; ++nt){
        acc[nt] = MFMA16(a_h, Bh[nt][kt], acc[nt]);
        acc[nt] = MFMA16(a_h, Bl[nt][kt], acc[nt]);
        acc[nt] = MFMA16(a_l, Bh[nt][kt], acc[nt]);
      }
    }
    #pragma unroll
    for (int nt = 0; nt < 4; ++nt){
      const int col = wv*64 + nt*16 + (lane & 15);
      #pragma unroll
      for (int r = 0; r < 4; ++r)
        gat[((lane >> 4)*4 + r)*512 + col] = acc[nt][r];
    }
    __syncthreads();
    // cell update: thread handles (seq srow+4i, hidden k)
    #pragma unroll
    for (int i = 0; i < 4; ++i){
      const int s = srow + 4*i;
      float p0 = gat[s*512 +       k] + xc[i][0] + bv[0];
      float p1 = gat[s*512 + 128 + k] + xc[i][1] + bv[1];
      float p2 = gat[s*512 + 256 + k] + xc[i][2] + bv[2];
      float p3 = gat[s*512 + 384 + k] + xc[i][3] + bv[3];
      float ig = sig_fast(p0), fg = sig_fast(p1);
      float gg = tanh_fast(p2), og = sig_fast(p3);
      c[i] = fg*c[i] + ig*gg;
      float h = og*tanh_fast(c[i]);
      if (s < ns) out[((long)(sbase + s)*T + t)*256 + dirOff + k] = h;
      _Float16 hh = (_Float16)h;
      Ah[((k >> 3)*16 + s)*8 + (k & 7)] = hh;
      Al[((k >> 3)*16 + s)*8 + (k & 7)] = (_Float16)(h - (float)hh);
      xc[i][0] = xn[i][0]; xc[i][1] = xn[i][1];
      xc[i][2] = xn[i][2]; xc[i][3] = xn[i][3];
    }
    __syncthreads();
  }
}

__global__ __launch_bounds__(256)
void k_gate(const float* __restrict__ in, const float* __restrict__ w,
            const float* __restrict__ b, float* __restrict__ out, int R)
{
  int row = blockIdx.x*4 + (threadIdx.x >> 6);
  int lane = threadIdx.x & 63;
  if (row >= R) return;
  const float* p = in + (long)row*256;
  float s = 0.f;
  #pragma unroll
  for (int j = 0; j < 4; ++j) s += p[lane + j*64]*w[lane + j*64];
  #pragma unroll
  for (int off = 32; off; off >>= 1) s += __shfl_down(s, off);
  if (lane == 0) out[row] = sigf(s + b[0]) + 1e-8f;
}

// an row-softmax -> fp16 hi/lo; feat_col = {max, mean}; shfl-based reductions
__global__ __launch_bounds__(256)
void k_an_feat16(const float* __restrict__ Mq, _Float16* __restrict__ anh,
                 _Float16* __restrict__ anl, float* __restrict__ feat)
{
  long r = blockIdx.x;
  int t = threadIdx.x;
  const int wid = t >> 6, lane = t & 63;
  float v = Mq[r*256 + t];
  float mx = v, sv = v;
  #pragma unroll
  for (int off = 32; off; off >>= 1){
    mx = fmaxf(mx, __shfl_down(mx, off));
    sv += __shfl_down(sv, off);
  }
  __shared__ float wmx[4], wsv[4], wse[4];
  if (lane == 0){ wmx[wid] = mx; wsv[wid] = sv; }
  __syncthreads();
  mx = fmaxf(fmaxf(wmx[0],wmx[1]), fmaxf(wmx[2],wmx[3]));
  sv = (wsv[0]+wsv[1]) + (wsv[2]+wsv[3]);
  float e = fexp(v - mx);
  float se = e;
  #pragma unroll
  for (int off = 32; off; off >>= 1) se += __shfl_down(se, off);
  if (lane == 0) wse[wid] = se;
  __syncthreads();
  se = (wse[0]+wse[1]) + (wse[2]+wse[3]);
  float a = e / se;
  _Float16 h = (_Float16)a;
  anh[r*256 + t] = h;
  anl[r*256 + t] = (_Float16)(a - (float)h);
  if (t == 0){ feat[r*2] = mx; feat[r*2+1] = sv*(1.f/256.f); }
}

// bn softmax over q -> TRANSPOSED fp16 hi/lo [bn][l=256][q padded 128]; feat_row
__global__ __launch_bounds__(1024)
void k_bn_feat16(const float* __restrict__ Mq, _Float16* __restrict__ bth,
                 _Float16* __restrict__ btl, float* __restrict__ feat)
{
  int bn = blockIdx.x;
  int t = threadIdx.x;
  int l = t & 255, qg = t >> 8;
  const float* Mb = Mq + (long)bn*25600;
  const int q0 = qg*25, q1 = q0 + 25;
  float mx = -3.4e38f, sv = 0.f;
  for (int q = q0; q < q1; ++q){ float v = Mb[q*256 + l]; mx = fmaxf(mx, v); sv += v; }
  __shared__ float smx[4][256], ssv[4][256], sse[4][256];
  smx[qg][l] = mx; ssv[qg][l] = sv;
  __syncthreads();
  mx = fmaxf(fmaxf(smx[0][l],smx[1][l]), fmaxf(smx[2][l],smx[3][l]));
  sv = (ssv[0][l]+ssv[1][l]) + (ssv[2][l]+ssv[3][l]);
  float se = 0.f;
  for (int q = q0; q < q1; ++q) se += fexp(Mb[q*256 + l] - mx);
  sse[qg][l] = se;
  __syncthreads();
  se = (sse[0][l]+sse[1][l]) + (sse[2][l]+sse[3][l]);
  float inv = 1.f/se;
  long base = ((long)bn*256 + l)*128;
  for (int q = q0; q < q1; ++q){
    float a = fexp(Mb[q*256 + l] - mx)*inv;
    _Float16 h = (_Float16)a;
    bth[base + q] = h;
    btl[base + q] = (_Float16)(a - (float)h);
  }
  if (qg == 0){
    for (int q = 100; q < 128; ++q){ bth[base+q] = (_Float16)0.f; btl[base+q] = (_Float16)0.f; }
    long fr = (long)(bn*256 + l)*2;
    feat[fr] = mx; feat[fr+1] = sv*0.01f;
  }
}

__global__ __launch_bounds__(256)
void k_copy_to_x(const float* __restrict__ D, float* __restrict__ X)
{
  long idx = (long)blockIdx.x*256 + threadIdx.x;
  long r = idx >> 8; int d = idx & 255;
  X[r*512 + d] = D[idx];
}

__global__ __launch_bounds__(256)
void k_split_hl(const float* __restrict__ x, _Float16* __restrict__ h,
                _Float16* __restrict__ l, long n)
{
  long i = (long)blockIdx.x*256 + threadIdx.x;
  if (i >= n) return;
  float v = x[i];
  _Float16 hi = (_Float16)v;
  h[i] = hi;
  l[i] = (_Float16)(v - (float)hi);
}

// generic batched transpose+split
__global__ __launch_bounds__(256)
void k_transp_hl(const float* __restrict__ src, _Float16* __restrict__ th,
                 _Float16* __restrict__ tl, int R, int Kp, long sSrc, long sDst)
{
  __shared__ float tile[32][33];
  const int m0 = blockIdx.x*32, n0 = blockIdx.y*32, z = blockIdx.z;
  const float* S = src + (long)z*sSrc;
  const int tx = threadIdx.x & 31, ty = threadIdx.x >> 5;
  #pragma unroll
  for (int r = 0; r < 32; r += 8){
    int gr = m0 + ty + r;
    tile[ty+r][tx] = (gr < R) ? S[(long)gr*256 + n0 + tx] : 0.f;
  }
  __syncthreads();
  const long base = (long)z*sDst;
  #pragma unroll
  for (int r = 0; r < 32; r += 8){
    float v = tile[tx][ty+r];
    _Float16 h = (_Float16)v;
    long o2 = base + (long)(n0+ty+r)*Kp + m0+tx;
    th[o2] = h;
    tl[o2] = (_Float16)(v - (float)h);
  }
}

// per-b X transpose (2560x512 -> 512x2560), split
__global__ __launch_bounds__(256)
void k_transpose_hl(const float* __restrict__ X, _Float16* __restrict__ Th,
                    _Float16* __restrict__ Tl)
{
  __shared__ float tile[32][33];
  const int m0 = blockIdx.x*32, n0 = blockIdx.y*32, b = blockIdx.z;
  const float* Xb = X + (long)b*2560*512;
  const int tx = threadIdx.x & 31, ty = threadIdx.x >> 5;
  #pragma unroll
  for (int r = 0; r < 32; r += 8)
    tile[ty+r][tx] = Xb[(long)(m0+ty+r)*512 + n0+tx];
  __syncthreads();
  const long base = (long)b*512*2560;
  #pragma unroll
  for (int r = 0; r < 32; r += 8){
    float v = tile[tx][ty+r];
    _Float16 h = (_Float16)v;
    long o2 = base + (long)(n0+ty+r)*2560 + m0+tx;
    Th[o2] = h;
    Tl[o2] = (_Float16)(v - (float)h);
  }
}

// z-batched row softmax over 2560 cols: S + z*sS, outputs Sh/Sl + z*sP
__global__ __launch_bounds__(256)
void k_softmax2560_hl2(const float* __restrict__ Sb, long sS,
                       _Float16* __restrict__ Shb, _Float16* __restrict__ Slb,
                       long sP)
{
  const int z = blockIdx.y;
  const float* p = Sb + z*sS + (long)blockIdx.x*2560;
  _Float16* Sh = Shb + z*sP;
  _Float16* Sl = Slb + z*sP;
  long r = blockIdx.x;
  int t = threadIdx.x;
  float loc[10];
  float mx = -3.4e38f;
  #pragma unroll
  for (int i=0;i<10;++i){ loc[i] = p[t + i*256]; mx = fmaxf(mx, loc[i]); }
  __shared__ float red[256];
  red[t]=mx; __syncthreads();
  for (int s2=128;s2;s2>>=1){ if(t<s2) red[t]=fmaxf(red[t],red[t+s2]); __syncthreads(); }
  mx = red[0]; __syncthreads();
  float se=0.f;
  #pragma unroll
  for (int i=0;i<10;++i){ loc[i]=fexp(loc[i]-mx); se+=loc[i]; }
  red[t]=se; __syncthreads();
  for (int s2=128;s2;s2>>=1){ if(t<s2) red[t]+=red[t+s2]; __syncthreads(); }
  float inv = 1.f/red[0];
  #pragma unroll
  for (int i=0;i<10;++i){
    float v = loc[i]*inv;
    _Float16 h = (_Float16)v;
    Sh[r*2560 + t + i*256] = h;
    Sl[r*2560 + t + i*256] = (_Float16)(v - (float)h);
  }
}

// RnQ_in hi/lo fp16, K padded 258->288
__global__ __launch_bounds__(320)
void k_build_rnq16(const float* __restrict__ RnQ, const float* __restrict__ featc,
                   const float* __restrict__ gq, _Float16* __restrict__ oh,
                   _Float16* __restrict__ ol)
{
  int row = blockIdx.x;           // 10000
  int t = threadIdx.x;
  if (t >= 288) return;
  int b = row / 1000, q = row % 100;
  float g = gq[b*100 + q];
  float v = 0.f;
  if (t < 256)      v = RnQ[(long)row*256 + t]*g;
  else if (t < 258) v = featc[(long)row*2 + (t-256)]*g;
  _Float16 h = (_Float16)v;
  oh[(long)row*288 + t] = h;
  ol[(long)row*288 + t] = (_Float16)(v - (float)h);
}

// RmD_in hi/lo fp16, K padded 514->544
__global__ __launch_bounds__(256)
void k_build_rmd16(const float* __restrict__ RmD, const float* __restrict__ featr,
                   const float* __restrict__ gc, _Float16* __restrict__ oh,
                   _Float16* __restrict__ ol)
{
  int row = blockIdx.x;           // 25600
  float g = gc[row];
  for (int j = threadIdx.x; j < 544; j += 256){
    float v = 0.f;
    if (j < 512)      v = RmD[(long)row*512 + j]*g;
    else if (j < 514) v = featr[(long)row*2 + (j-512)]*g;
    _Float16 h = (_Float16)v;
    oh[(long)row*544 + j] = h;
    ol[(long)row*544 + j] = (_Float16)(v - (float)h);
  }
}

__global__ __launch_bounds__(256)
void k_maxt2(const float* __restrict__ hs0, float* __restrict__ o0, int S0, int T0,
             const float* __restrict__ hs1, float* __restrict__ o1, int T1)
{
  int x = blockIdx.x; int d = threadIdx.x;
  const float* hs; float* op; int T, s;
  if (x < S0){ hs = hs0; op = o0; T = T0; s = x; }
  else       { hs = hs1; op = o1; T = T1; s = x - S0; }
  float m = -3.4e38f;
  for (int t = 0; t < T; ++t) m = fmaxf(m, hs[((long)s*T + t)*256 + d]);
  op[s*256 + d] = m;
}

__global__ __launch_bounds__(512)
void k_final(const float* __restrict__ q_out, const float* __restrict__ c_out,
             const float* __restrict__ gnW, const float* __restrict__ gnB,
             const float* __restrict__ decW, const float* __restrict__ decB,
             const float* __restrict__ logics, float* __restrict__ out)
{
  int b = blockIdx.x;
  int t = threadIdx.x;
  __shared__ float red[512];
  float mx = -3.4e38f, sm = 0.f;
  for (int n = 0; n < 10; ++n) {
    int s = b*10 + n;
    float f = (t < 256) ? q_out[(long)s*256 + t] : c_out[(long)s*256 + (t-256)];
    red[t] = f * gnW[t]; __syncthreads();
    for (int st=256; st; st>>=1){ if (t<st) red[t]+=red[t+st]; __syncthreads(); }
    float g = sigf(red[0] + gnB[0]);
    __syncthreads();
    float gf = f*g;
    mx = fmaxf(mx, gf); sm += gf;
  }
  sm *= 0.1f;
  red[t] = mx*decW[t] + sm*decW[512 + t]; __syncthreads();
  for (int st=256; st; st>>=1){ if (t<st) red[t]+=red[t+st]; __syncthreads(); }
  if (t == 0) out[b] = (red[0] + decB[0]) * logics[b];
}

static inline int cdiv(int a, int b){ return (a + b - 1)/b; }

extern "C" void kernel_launch(void* const* d_in, const int* in_sizes, int n_in,
                              void* d_out, int out_size, void* d_ws, size_t ws_size,
                              hipStream_t stream)
{
  const int*   contents = (const int*)  d_in[0];
  const int*   qa       = (const int*)  d_in[1];
  const float* logics   = (const float*)d_in[2];
  const float* ef       = (const float*)d_in[3];
  const float* ed       = (const float*)d_in[4];
  const float* ctx_Wi   = (const float*)d_in[5];
  const float* ctx_Wh   = (const float*)d_in[6];
  const float* ctx_b    = (const float*)d_in[7];
  const float* qr_Wi    = (const float*)d_in[8];
  const float* qr_Wh    = (const float*)d_in[9];
  const float* qr_b     = (const float*)d_in[10];
  const float* cr_Wi    = (const float*)d_in[11];
  const float* cr_Wh    = (const float*)d_in[12];
  const float* cr_b     = (const float*)d_in[13];
  const float* grW      = (const float*)d_in[14];
  const float* grB      = (const float*)d_in[15];
  const float* gnW      = (const float*)d_in[16];
  const float* gnB      = (const float*)d_in[17];
  const float* decW     = (const float*)d_in[18];
  const float* decB     = (const float*)d_in[19];
  float* out = (float*)d_out;
  float* w = (float*)d_ws;

  const long RU = 26624;                    // unified embed/proj rows (208*128)
  size_t o = 0;
  auto alloc = [&](size_t n){ size_t r = o; o += (n + 63) & ~(size_t)63; return r; };
  size_t cv16    = alloc((size_t)RU*224);   // dead after ctx proj
  size_t ctxW16  = alloc(1024u*224);
  size_t qrW16   = alloc(1024u*288);
  size_t crW16   = alloc(1024u*544);
  size_t ctxWr   = alloc(131072);           // recurrent Wh transposed fp16 hi+lo
  size_t qrWr    = alloc(131072);
  size_t crWr    = alloc(131072);
  size_t c_xg    = alloc((size_t)RU*1024);  // rows 25600.. = q_xg; reused attn fp16 + cr_xg
  size_t q_enc   = alloc(1000u*256);
  size_t D_enc   = alloc(25600u*256);
  size_t gate_q  = alloc(1000);
  size_t gate_c  = alloc(25600);
  size_t M_qc    = alloc(2560000);          // reused for S pair-0 fp16 during attention
  size_t an_     = alloc(2560000);          // an fp16 hi/lo overlay
  size_t bn_     = alloc(3276800);          // bnT fp16 hi/lo [100][256][128]
  size_t featc   = alloc(20000);
  size_t featr   = alloc(51200);
  size_t RnQ     = alloc(2560000);
  size_t Xb      = alloc(10u*2560*512);
  size_t Sbuf    = alloc(6553600);          // attn S z=0 (f32); D16t overlay pre-attention
  size_t RmD     = alloc(10u*2560*512);     // D16 overlay pre-attention
  size_t rnq16   = alloc(10000u*288);
  size_t qr_xg   = alloc(10000u*1024);      // attn S z=1 overlay during attention
  size_t q_hs    = alloc(100u*100*256);     // q16/q16t overlay pre-qr-LSTM
  size_t rmd16   = alloc(25600u*544);       // Sh2/Sl2 overlay during attention
  size_t c_hs    = alloc(100u*256*256);
  size_t q_out   = alloc(100u*256);
  size_t c_out   = alloc(100u*256);

  if (ws_size < o*sizeof(float)) {
    k_sentinel<<<1,64,0,stream>>>(out, out_size);
    return;
  }

  // fp16 views
  _Float16* cvh = (_Float16*)(w + cv16);       _Float16* cvl = cvh + RU*224;
  _Float16* cWh = (_Float16*)(w + ctxW16);     _Float16* cWl = cWh + 1024L*224;
  _Float16* qWh = (_Float16*)(w + qrW16);      _Float16* qWl = qWh + 1024L*288;
  _Float16* rWh = (_Float16*)(w + crW16);      _Float16* rWl = rWh + 1024L*544;
  _Float16* cRh = (_Float16*)(w + ctxWr);      _Float16* cRl = cRh + 131072L;
  _Float16* qRh = (_Float16*)(w + qrWr);       _Float16* qRl = qRh + 131072L;
  _Float16* rRh = (_Float16*)(w + crWr);       _Float16* rRl = rRh + 131072L;
  _Float16* nqh = (_Float16*)(w + rnq16);      _Float16* nql = nqh + 10000L*288;
  _Float16* mdh = (_Float16*)(w + rmd16);      _Float16* mdl = mdh + 25600L*544;
  // attention overlays (dead-region reuse)
  _Float16* Xh  = (_Float16*)(w + c_xg);       // 4 x 13,107,200 halves <= c_xg
  _Float16* Xl  = Xh  + 13107200L;
  _Float16* Xth = Xl  + 13107200L;
  _Float16* Xtl = Xth + 13107200L;
  _Float16* Sh  = (_Float16*)(w + M_qc);       // pair-0: 2 x 6,553,600 halves <= M_qc..bn_
  _Float16* Sl  = Sh + 6553600L;
  // pair-1 S buffers (dead regions during attention)
  float*    S2  = w + qr_xg;                   // 6,553,600 <= 10,240,000 floats
  _Float16* Sh2 = (_Float16*)(w + rmd16);      // 2 x 6,553,600 halves <= rmd16
  _Float16* Sl2 = Sh2 + 6553600L;
  const long sS_pair = (long)(S2 - (w + Sbuf));          // float stride z0->z1
  const long sP_pair = (long)(Sh2 - Sh);                 // fp16 stride z0->z1
  // pre-attention fp16 overlays
  _Float16* anh = (_Float16*)(w + an_);        _Float16* anl = anh + 2560000L;
  _Float16* bth = (_Float16*)(w + bn_);        _Float16* btl = bth + 3276800L;
  _Float16* D16h = (_Float16*)(w + RmD);       _Float16* D16l = D16h + 6553600L;   // row-major
  _Float16* Dt16h = (_Float16*)(w + Sbuf);     _Float16* Dt16l = Dt16h + 6553600L; // transposed
  _Float16* q16h = (_Float16*)(w + q_hs);      _Float16* q16l = q16h + 256000L;
  _Float16* qt16h = q16l + 256000L;            _Float16* qt16l = qt16h + 327680L;  // [b][256][128]
  float* q_xg_p = w + c_xg + 25600L*1024;

  // --- weight transforms + unified embeddings ---
  k_wsplit<<<1024,256,0,stream>>>(ctx_Wi, cWh, cWl, 200, 224);
  k_wsplit<<<1024,256,0,stream>>>(qr_Wi,  qWh, qWl, 258, 288);
  k_wsplit<<<1024,256,0,stream>>>(cr_Wi,  rWh, rWl, 514, 544);
  k_wsplit<<<1024,256,0,stream>>>(ctx_Wh, cRh, cRl, 128, 128);
  k_wsplit<<<1024,256,0,stream>>>(qr_Wh,  qRh, qRl, 128, 128);
  k_wsplit<<<1024,256,0,stream>>>(cr_Wh,  rRh, rRl, 128, 128);
  k_embed16u<<<(int)RU, 256, 0, stream>>>(contents, qa, ef, ed, cvh, cvl, 224);

  // --- ctx input projection (content + question, one dispatch) ---
  k_mfma<<<dim3(208,8,1),256,0,stream>>>(cvh, cvl, cWh, cWl, w+c_xg,
      (int)RU, 224, 1024, 1024, 0L,0L,0L, 1,1, 3);

  // --- ctx LSTMs via MFMA (content 7 chunks T=256 + question 1 chunk T=100) ---
  k_lstm_mf<<<dim3(8,2),512,0,stream>>>(
      w+c_xg, cRh, cRl, ctx_b, w+D_enc, 7, 100, 256,
      q_xg_p, cRh, cRl, ctx_b, w+q_enc, 10, 100);

  // --- reasoning gates ---
  k_gate<<<cdiv(1000,4),256,0,stream>>>(w+q_enc, grW, grB, w+gate_q, 1000);
  k_gate<<<cdiv(25600,4),256,0,stream>>>(w+D_enc, grW, grB, w+gate_c, 25600);

  // --- fp16 operand prep for matching GEMMs ---
  k_split_hl<<<cdiv(6553600,256),256,0,stream>>>(w+D_enc, D16h, D16l, 6553600L);
  k_split_hl<<<cdiv(256000,256),256,0,stream>>>(w+q_enc, q16h, q16l, 256000L);
  k_transp_hl<<<dim3(8,8,100),256,0,stream>>>(w+D_enc, Dt16h, Dt16l, 256, 256, 65536L, 65536L);
  k_transp_hl<<<dim3(4,8,10),256,0,stream>>>(w+q_enc, qt16h, qt16l, 100, 128, 25600L, 32768L);

  // --- M_qc[bn] = q_enc[b] @ D_enc[bn]^T  (MFMA, z=100) ---
  k_mfma<<<dim3(1,2,100),256,0,stream>>>(q16h, q16l, D16h, D16l, w+M_qc,
      100, 256, 256, 256, 25600L, 65536L, 25600L, 10, 1, 3);

  // --- softmaxes + feats (emit fp16 splits directly) ---
  k_an_feat16<<<10000,256,0,stream>>>(w+M_qc, anh, anl, w+featc);
  k_bn_feat16<<<100,1024,0,stream>>>(w+M_qc, bth, btl, w+featr);

  // --- RnQ = an @ D_enc ---
  k_mfma<<<dim3(1,2,100),256,0,stream>>>(anh, anl, Dt16h, Dt16l, w+RnQ,
      100, 256, 256, 256, 25600L, 65536L, 25600L, 1, 1, 3);

  // --- RnD = bn^T @ q_enc -> X[...,256:512] ---
  k_mfma<<<dim3(2,2,100),256,0,stream>>>(bth, btl, qt16h, qt16l, w+Xb+256,
      256, 128, 256, 512, 32768L, 32768L, 131072L, 1, 10, 3);

  // --- X[...,0:256] = D_enc ---
  k_copy_to_x<<<25600,256,0,stream>>>(w+D_enc, w+Xb);

  // --- fp16 splits of X (row-major and transposed) ---
  k_split_hl<<<51200,256,0,stream>>>(w+Xb, Xh, Xl, 13107200L);
  k_transpose_hl<<<dim3(80,16,10),256,0,stream>>>(w+Xb, Xth, Xtl);

  // --- cross-doc attention, 2 b's per iteration (z-batched), 2-pass MFMA ---
  for (int bp = 0; bp < 5; ++bp) {
    const long xo = (long)bp*2*1310720;
    k_mfma<<<dim3(20,20,2),256,0,stream>>>(Xh+xo, Xl+xo, Xh+xo, Xl+xo, w+Sbuf,
        2560, 512, 2560, 2560, 1310720L, 1310720L, sS_pair, 1, 1, 2);
    k_softmax2560_hl2<<<dim3(2560,2),256,0,stream>>>(w+Sbuf, sS_pair, Sh, Sl, sP_pair);
    k_mfma<<<dim3(20,4,2),256,0,stream>>>(Sh, Sl, Xth+xo, Xtl+xo, w+RmD+xo,
        2560, 2560, 512, 512, sP_pair, 1310720L, 1310720L, 1, 1, 2);
  }

  // --- qr + cr input builds and projections ---
  k_build_rnq16<<<10000,320,0,stream>>>(w+RnQ, w+featc, w+gate_q, nqh, nql);
  k_mfma<<<dim3(79,8,1),256,0,stream>>>(nqh, nql, qWh, qWl, w+qr_xg,
      10000, 288, 1024, 1024, 0L,0L,0L, 1,1, 3);
  k_build_rmd16<<<25600,256,0,stream>>>(w+RmD, w+featr, w+gate_c, mdh, mdl);
  k_mfma<<<dim3(200,8,1),256,0,stream>>>(mdh, mdl, rWh, rWl, w+c_xg,
      25600, 544, 1024, 1024, 0L,0L,0L, 1,1, 3);

  // --- qr + cr LSTMs via MFMA (cr 7 chunks T=256 + qr 7 chunks T=100) ---
  k_lstm_mf<<<dim3(14,2),512,0,stream>>>(
      w+c_xg, rRh, rRl, cr_b, w+c_hs, 7, 100, 256,
      w+qr_xg, qRh, qRl, qr_b, w+q_hs, 100, 100);

  // --- max over time ---
  k_maxt2<<<200,256,0,stream>>>(w+c_hs, w+c_out, 100, 256, w+q_hs, w+q_out, 100);

  // --- decode head ---
  k_final<<<10,512,0,stream>>>(w+q_out, w+c_out, gnW, gnB, decW, decB, logics, out);
}

// Round 13
// 1873.666 us; speedup vs baseline: 1.4119x; 1.4119x over previous
//
#include <hip/hip_runtime.h>
#include <cstdint>
#include <cstddef>

typedef __attribute__((ext_vector_type(8))) _Float16 half8;
typedef __attribute__((ext_vector_type(4))) float f32x4;

__device__ __forceinline__ float fexp(float x){ return __expf(x); }
__device__ __forceinline__ float sig_fast(float x){
  return __builtin_amdgcn_rcpf(1.f + __expf(-x));
}
__device__ __forceinline__ float tanh_fast(float x){
  return 2.f*__builtin_amdgcn_rcpf(1.f + __expf(-2.f*x)) - 1.f;
}
__device__ __forceinline__ float sigf(float x){ return 1.0f/(1.0f+expf(-x)); }

__device__ __forceinline__ void async_lds16(const _Float16* g, _Float16* l){
  __builtin_amdgcn_global_load_lds(
      (const __attribute__((address_space(1))) void*)g,
      (__attribute__((address_space(3))) void*)l, 16, 0, 0);
}

__global__ __launch_bounds__(64)
void k_sentinel(float* out, int n){ int i=threadIdx.x; if(i<n) out[i]=1.0e9f; }

// unified embeddings: rows 0..25599 = contents, 25600..26599 = question, rest zero
__global__ __launch_bounds__(256)
void k_embed16u(const int* __restrict__ c_tok, const int* __restrict__ q_tok,
                const float* __restrict__ ef, const float* __restrict__ ed,
                _Float16* __restrict__ oh, _Float16* __restrict__ ol, int Kpad)
{
  int t = blockIdx.x; int e = threadIdx.x;
  if (e >= Kpad) return;
  _Float16 h = (_Float16)0.f, l = (_Float16)0.f;
  int tok = -1;
  if (t < 25600) tok = c_tok[t];
  else if (t < 26600) tok = q_tok[t - 25600];
  if (tok >= 0 && e < 200){
    long r = (long)tok*200 + e;
    float v = ef[r] + ed[r];
    h = (_Float16)v; l = (_Float16)(v - (float)h);
  }
  oh[(long)t*Kpad + e] = h;
  ol[(long)t*Kpad + e] = l;
}

// W[2][K][512] -> Wt_h/Wt_l[(dir*512+n)][Kpad]
__global__ __launch_bounds__(256)
void k_wsplit(const float* __restrict__ W, _Float16* __restrict__ th,
              _Float16* __restrict__ tl, int K, int Kpad)
{
  int n = blockIdx.x;               // 0..1023
  int dir = n >> 9, col = n & 511;
  for (int k = threadIdx.x; k < Kpad; k += 256){
    _Float16 h = (_Float16)0.f, l = (_Float16)0.f;
    if (k < K){
      float v = W[((long)dir*K + k)*512 + col];
      h = (_Float16)v; l = (_Float16)(v - (float)h);
    }
    th[(long)n*Kpad + k] = h;
    tl[(long)n*Kpad + k] = l;
  }
}

// ---------------- split-fp16 MFMA GEMM, z-batched, 2/3-pass, f32 or fp16 out --
#define MFMA16(a,b,c) __builtin_amdgcn_mfma_f32_16x16x32_f16(a,b,c,0,0,0)

__global__ __launch_bounds__(256, 2)
void k_mfma(const _Float16* __restrict__ Ahb, const _Float16* __restrict__ Alb,
            const _Float16* __restrict__ Bhb, const _Float16* __restrict__ Blb,
            float* __restrict__ Cb, int M, int K, int N, int ldc,
            long sA, long sB, long sC, int divA, int divB, int passes,
            _Float16* __restrict__ Chb, _Float16* __restrict__ Clb, long sCh)
{
  const int z = blockIdx.z;
  const _Float16* Ah = Ahb + (long)(z/divA)*sA;
  const _Float16* Al = Alb + (long)(z/divA)*sA;
  const _Float16* Bh = Bhb + (long)(z/divB)*sB;
  const _Float16* Bl = Blb + (long)(z/divB)*sB;

  const int m0 = blockIdx.x*128, n0 = blockIdx.y*128;
  const int tid = threadIdx.x;
  const int lane = tid & 63, wave = tid >> 6;
  const int wm = wave >> 1, wn = wave & 1;     // 2x2 waves, 64x64 per wave

  __shared__ _Float16 lds[2][2048*8];

  f32x4 acc[4][4] = {};

  const int KT = K >> 5;
  const bool p3 = (passes == 3);

  auto STAGE = [&](int buf, int kt){
    const int k0 = kt*32;
    #pragma unroll
    for (int it = 0; it < 8; ++it){
      const int c  = it*256 + tid;
      const int op = it >> 1;
      if (!p3 && op == 1) continue;          // Al unused in 2-pass: skip staging
      const int kb = (c >> 7) & 3;
      const int row = c & 127;
      const _Float16* base = (op==0) ? Ah : (op==1) ? Al : (op==2) ? Bh : Bl;
      int gr = (op < 2) ? (m0 + row) : (n0 + row);
      if (op < 2 && gr >= M) gr = M - 1;
      const _Float16* src = base + (long)gr*K + k0 + kb*8;
      _Float16* dst = &lds[buf][(size_t)(it*256 + (tid & ~63))*8];
      async_lds16(src, dst);
    }
  };

  auto COMPUTE = [&](int buf){
    const int kb = lane >> 4, r = lane & 15;
    half8 ah[4], al[4], bh[4], bl[4];
    #pragma unroll
    for (int mi = 0; mi < 4; ++mi){
      ah[mi] = *(const half8*)&lds[buf][(size_t)(        kb*128 + wm*64 + mi*16 + r)*8];
      if (p3) al[mi] = *(const half8*)&lds[buf][(size_t)( 512 + kb*128 + wm*64 + mi*16 + r)*8];
    }
    #pragma unroll
    for (int ni = 0; ni < 4; ++ni){
      bh[ni] = *(const half8*)&lds[buf][(size_t)(1024 + kb*128 + wn*64 + ni*16 + r)*8];
      bl[ni] = *(const half8*)&lds[buf][(size_t)(1536 + kb*128 + wn*64 + ni*16 + r)*8];
    }
    #pragma unroll
    for (int mi = 0; mi < 4; ++mi)
      #pragma unroll
      for (int ni = 0; ni < 4; ++ni){
        acc[mi][ni] = MFMA16(ah[mi], bh[ni], acc[mi][ni]);
        acc[mi][ni] = MFMA16(ah[mi], bl[ni], acc[mi][ni]);
        if (p3) acc[mi][ni] = MFMA16(al[mi], bh[ni], acc[mi][ni]);
      }
  };

  STAGE(0, 0);
  for (int kt = 0; kt < KT; ++kt){
    __syncthreads();
    if (kt + 1 < KT) STAGE((kt+1)&1, kt+1);
    COMPUTE(kt&1);
  }

  const int r4 = (lane >> 4) * 4, cN = lane & 15;
  if (Chb){
    _Float16* Ch = Chb + (long)z*sCh;
    _Float16* Cl = Clb + (long)z*sCh;
    #pragma unroll
    for (int mi = 0; mi < 4; ++mi)
      #pragma unroll
      for (int ni = 0; ni < 4; ++ni){
        const int row = m0 + wm*64 + mi*16 + r4;
        const int col = n0 + wn*64 + ni*16 + cN;
        #pragma unroll
        for (int r = 0; r < 4; ++r)
          if (row + r < M){
            float v = acc[mi][ni][r];
            _Float16 hh = (_Float16)v;
            long idx = (long)(row + r)*ldc + col;
            Ch[idx] = hh;
            Cl[idx] = (_Float16)(v - (float)hh);
          }
      }
  } else {
    float* C = Cb + (long)z*sC;
    #pragma unroll
    for (int mi = 0; mi < 4; ++mi)
      #pragma unroll
      for (int ni = 0; ni < 4; ++ni){
        const int row = m0 + wm*64 + mi*16 + r4;
        const int col = n0 + wn*64 + ni*16 + cN;
        #pragma unroll
        for (int r = 0; r < 4; ++r)
          if (row + r < M) C[(long)(row + r)*ldc + col] = acc[mi][ni][r];
      }
  }
}

// ---------------- merged 2-job LSTM scan (R9/R11 form: empirical best) -------
__global__ __launch_bounds__(512, 1)
void k_lstm2(const float* __restrict__ xg0, const float* __restrict__ Wh0,
             const float* __restrict__ bs0, float* __restrict__ out0,
             int S0, int T0, int ldx0,
             const float* __restrict__ xg1, const float* __restrict__ Wh1,
             const float* __restrict__ bs1, float* __restrict__ out1,
             int T1, int ldx1)
{
  const int bx = blockIdx.x;
  const int dir = blockIdx.y;
  const float* xg; const float* Whb; const float* bsb; float* out;
  int T, ldx, s;
  if (bx < S0){ s = bx;      xg = xg0; Whb = Wh0; bsb = bs0; out = out0; T = T0; ldx = ldx0; }
  else        { s = bx - S0; xg = xg1; Whb = Wh1; bsb = bs1; out = out1; T = T1; ldx = ldx1; }
  xg += dir*512;
  const float* Wh = Whb + (long)dir*128*512;
  const int dirOff = dir*128;
  const int k = threadIdx.x;
  const float bv = bsb[dir*512 + k];

  // Wh column k cached in 32 float4 VGPRs (compiler re-fetches via L2/L1;
  // 414us = per-CU L1 streaming floor. 5 alternatives all failed: R5-R12.)
  float4 wv[32];
  #pragma unroll
  for (int j = 0; j < 32; ++j){
    wv[j].x = Wh[(j*4+0)*512 + k];
    wv[j].y = Wh[(j*4+1)*512 + k];
    wv[j].z = Wh[(j*4+2)*512 + k];
    wv[j].w = Wh[(j*4+3)*512 + k];
  }

  __shared__ __align__(16) float h_lds[128];
  __shared__ float a_lds[512];
  float c = 0.f;
  if (k < 128) h_lds[k] = 0.f;
  __syncthreads();

  float gcur = xg[((long)s*T + (dir ? T-1 : 0))*ldx + k];

  for (int tt = 0; tt < T; ++tt) {
    const int t = dir ? (T-1-tt) : tt;
    float gnext = 0.f;
    if (tt + 1 < T){
      const int tn = dir ? (T-2-tt) : (tt+1);
      gnext = xg[((long)s*T + tn)*ldx + k];
    }
    float acc0 = gcur + bv, acc1 = 0.f, acc2 = 0.f, acc3 = 0.f;
    #pragma unroll
    for (int j = 0; j < 8; ++j) {
      float4 h0 = *(const float4*)&h_lds[(j*4+0)*4];
      float4 h1 = *(const float4*)&h_lds[(j*4+1)*4];
      float4 h2 = *(const float4*)&h_lds[(j*4+2)*4];
      float4 h3 = *(const float4*)&h_lds[(j*4+3)*4];
      acc0 += h0.x*wv[j*4+0].x + h0.y*wv[j*4+0].y + h0.z*wv[j*4+0].z + h0.w*wv[j*4+0].w;
      acc1 += h1.x*wv[j*4+1].x + h1.y*wv[j*4+1].y + h1.z*wv[j*4+1].z + h1.w*wv[j*4+1].w;
      acc2 += h2.x*wv[j*4+2].x + h2.y*wv[j*4+2].y + h2.z*wv[j*4+2].z + h2.w*wv[j*4+2].w;
      acc3 += h3.x*wv[j*4+3].x + h3.y*wv[j*4+3].y + h3.z*wv[j*4+3].z + h3.w*wv[j*4+3].w;
    }
    float g = (acc0 + acc1) + (acc2 + acc3);
    a_lds[k] = ((k >> 7) == 2) ? tanh_fast(g) : sig_fast(g);
    __syncthreads();
    if (k < 128) {
      float ig = a_lds[k];
      float fg = a_lds[k+128];
      float gg = a_lds[k+256];
      float og = a_lds[k+384];
      c = fg*c + ig*gg;
      float h = og*tanh_fast(c);
      h_lds[k] = h;
      out[((long)s*T + t)*256 + dirOff + k] = h;
    }
    __syncthreads();
    gcur = gnext;
  }
}

__global__ __launch_bounds__(256)
void k_gate(const float* __restrict__ in, const float* __restrict__ w,
            const float* __restrict__ b, float* __restrict__ out, int R)
{
  int row = blockIdx.x*4 + (threadIdx.x >> 6);
  int lane = threadIdx.x & 63;
  if (row >= R) return;
  const float* p = in + (long)row*256;
  float s = 0.f;
  #pragma unroll
  for (int j = 0; j < 4; ++j) s += p[lane + j*64]*w[lane + j*64];
  #pragma unroll
  for (int off = 32; off; off >>= 1) s += __shfl_down(s, off);
  if (lane == 0) out[row] = sigf(s + b[0]) + 1e-8f;
}

// an row-softmax -> fp16 hi/lo; feat_col = {max, mean}; shfl-based reductions
__global__ __launch_bounds__(256)
void k_an_feat16(const float* __restrict__ Mq, _Float16* __restrict__ anh,
                 _Float16* __restrict__ anl, float* __restrict__ feat)
{
  long r = blockIdx.x;
  int t = threadIdx.x;
  const int wid = t >> 6, lane = t & 63;
  float v = Mq[r*256 + t];
  float mx = v, sv = v;
  #pragma unroll
  for (int off = 32; off; off >>= 1){
    mx = fmaxf(mx, __shfl_down(mx, off));
    sv += __shfl_down(sv, off);
  }
  __shared__ float wmx[4], wsv[4], wse[4];
  if (lane == 0){ wmx[wid] = mx; wsv[wid] = sv; }
  __syncthreads();
  mx = fmaxf(fmaxf(wmx[0],wmx[1]), fmaxf(wmx[2],wmx[3]));
  sv = (wsv[0]+wsv[1]) + (wsv[2]+wsv[3]);
  float e = fexp(v - mx);
  float se = e;
  #pragma unroll
  for (int off = 32; off; off >>= 1) se += __shfl_down(se, off);
  if (lane == 0) wse[wid] = se;
  __syncthreads();
  se = (wse[0]+wse[1]) + (wse[2]+wse[3]);
  float a = e / se;
  _Float16 h = (_Float16)a;
  anh[r*256 + t] = h;
  anl[r*256 + t] = (_Float16)(a - (float)h);
  if (t == 0){ feat[r*2] = mx; feat[r*2+1] = sv*(1.f/256.f); }
}

// bn softmax over q -> TRANSPOSED fp16 hi/lo [bn][l=256][q padded 128]; feat_row
__global__ __launch_bounds__(1024)
void k_bn_feat16(const float* __restrict__ Mq, _Float16* __restrict__ bth,
                 _Float16* __restrict__ btl, float* __restrict__ feat)
{
  int bn = blockIdx.x;
  int t = threadIdx.x;
  int l = t & 255, qg = t >> 8;
  const float* Mb = Mq + (long)bn*25600;
  const int q0 = qg*25, q1 = q0 + 25;
  float mx = -3.4e38f, sv = 0.f;
  for (int q = q0; q < q1; ++q){ float v = Mb[q*256 + l]; mx = fmaxf(mx, v); sv += v; }
  __shared__ float smx[4][256], ssv[4][256], sse[4][256];
  smx[qg][l] = mx; ssv[qg][l] = sv;
  __syncthreads();
  mx = fmaxf(fmaxf(smx[0][l],smx[1][l]), fmaxf(smx[2][l],smx[3][l]));
  sv = (ssv[0][l]+ssv[1][l]) + (ssv[2][l]+ssv[3][l]);
  float se = 0.f;
  for (int q = q0; q < q1; ++q) se += fexp(Mb[q*256 + l] - mx);
  sse[qg][l] = se;
  __syncthreads();
  se = (sse[0][l]+sse[1][l]) + (sse[2][l]+sse[3][l]);
  float inv = 1.f/se;
  long base = ((long)bn*256 + l)*128;
  for (int q = q0; q < q1; ++q){
    float a = fexp(Mb[q*256 + l] - mx)*inv;
    _Float16 h = (_Float16)a;
    bth[base + q] = h;
    btl[base + q] = (_Float16)(a - (float)h);
  }
  if (qg == 0){
    for (int q = 100; q < 128; ++q){ bth[base+q] = (_Float16)0.f; btl[base+q] = (_Float16)0.f; }
    long fr = (long)(bn*256 + l)*2;
    feat[fr] = mx; feat[fr+1] = sv*0.01f;
  }
}

__global__ __launch_bounds__(256)
void k_copy_to_x(const float* __restrict__ D, float* __restrict__ X)
{
  long idx = (long)blockIdx.x*256 + threadIdx.x;
  long r = idx >> 8; int d = idx & 255;
  X[r*512 + d] = D[idx];
}

__global__ __launch_bounds__(256)
void k_split_hl(const float* __restrict__ x, _Float16* __restrict__ h,
                _Float16* __restrict__ l, long n)
{
  long i = (long)blockIdx.x*256 + threadIdx.x;
  if (i >= n) return;
  float v = x[i];
  _Float16 hi = (_Float16)v;
  h[i] = hi;
  l[i] = (_Float16)(v - (float)hi);
}

// generic batched transpose+split
__global__ __launch_bounds__(256)
void k_transp_hl(const float* __restrict__ src, _Float16* __restrict__ th,
                 _Float16* __restrict__ tl, int R, int Kp, long sSrc, long sDst)
{
  __shared__ float tile[32][33];
  const int m0 = blockIdx.x*32, n0 = blockIdx.y*32, z = blockIdx.z;
  const float* S = src + (long)z*sSrc;
  const int tx = threadIdx.x & 31, ty = threadIdx.x >> 5;
  #pragma unroll
  for (int r = 0; r < 32; r += 8){
    int gr = m0 + ty + r;
    tile[ty+r][tx] = (gr < R) ? S[(long)gr*256 + n0 + tx] : 0.f;
  }
  __syncthreads();
  const long base = (long)z*sDst;
  #pragma unroll
  for (int r = 0; r < 32; r += 8){
    float v = tile[tx][ty+r];
    _Float16 h = (_Float16)v;
    long o2 = base + (long)(n0+ty+r)*Kp + m0+tx;
    th[o2] = h;
    tl[o2] = (_Float16)(v - (float)h);
  }
}

// per-b X transpose (2560x512 -> 512x2560), split
__global__ __launch_bounds__(256)
void k_transpose_hl(const float* __restrict__ X, _Float16* __restrict__ Th,
                    _Float16* __restrict__ Tl)
{
  __shared__ float tile[32][33];
  const int m0 = blockIdx.x*32, n0 = blockIdx.y*32, b = blockIdx.z;
  const float* Xb = X + (long)b*2560*512;
  const int tx = threadIdx.x & 31, ty = threadIdx.x >> 5;
  #pragma unroll
  for (int r = 0; r < 32; r += 8)
    tile[ty+r][tx] = Xb[(long)(m0+ty+r)*512 + n0+tx];
  __syncthreads();
  const long base = (long)b*512*2560;
  #pragma unroll
  for (int r = 0; r < 32; r += 8){
    float v = tile[tx][ty+r];
    _Float16 h = (_Float16)v;
    long o2 = base + (long)(n0+ty+r)*2560 + m0+tx;
    Th[o2] = h;
    Tl[o2] = (_Float16)(v - (float)h);
  }
}

// z-batched IN-PLACE row softmax on fp16 hi/lo S slabs (v = hi + lo)
__global__ __launch_bounds__(256)
void k_softmax2560_io16(_Float16* __restrict__ ShA, _Float16* __restrict__ SlA,
                        long slab)
{
  const int z = blockIdx.y;
  _Float16* Sh = ShA + (long)z*slab;
  _Float16* Sl = SlA + (long)z*slab;
  long r = blockIdx.x;
  int t = threadIdx.x;
  float loc[10];
  float mx = -3.4e38f;
  #pragma unroll
  for (int i=0;i<10;++i){
    long idx = r*2560 + t + i*256;
    loc[i] = (float)Sh[idx] + (float)Sl[idx];
    mx = fmaxf(mx, loc[i]);
  }
  __shared__ float red[256];
  red[t]=mx; __syncthreads();
  for (int s2=128;s2;s2>>=1){ if(t<s2) red[t]=fmaxf(red[t],red[t+s2]); __syncthreads(); }
  mx = red[0]; __syncthreads();
  float se=0.f;
  #pragma unroll
  for (int i=0;i<10;++i){ loc[i]=fexp(loc[i]-mx); se+=loc[i]; }
  red[t]=se; __syncthreads();
  for (int s2=128;s2;s2>>=1){ if(t<s2) red[t]+=red[t+s2]; __syncthreads(); }
  float inv = 1.f/red[0];
  #pragma unroll
  for (int i=0;i<10;++i){
    float v = loc[i]*inv;
    _Float16 h = (_Float16)v;
    long idx = r*2560 + t + i*256;
    Sh[idx] = h;
    Sl[idx] = (_Float16)(v - (float)h);
  }
}

// RnQ_in hi/lo fp16, K padded 258->288
__global__ __launch_bounds__(320)
void k_build_rnq16(const float* __restrict__ RnQ, const float* __restrict__ featc,
                   const float* __restrict__ gq, _Float16* __restrict__ oh,
                   _Float16* __restrict__ ol)
{
  int row = blockIdx.x;           // 10000
  int t = threadIdx.x;
  if (t >= 288) return;
  int b = row / 1000, q = row % 100;
  float g = gq[b*100 + q];
  float v = 0.f;
  if (t < 256)      v = RnQ[(long)row*256 + t]*g;
  else if (t < 258) v = featc[(long)row*2 + (t-256)]*g;
  _Float16 h = (_Float16)v;
  oh[(long)row*288 + t] = h;
  ol[(long)row*288 + t] = (_Float16)(v - (float)h);
}

// RmD_in hi/lo fp16, K padded 514->544
__global__ __launch_bounds__(256)
void k_build_rmd16(const float* __restrict__ RmD, const float* __restrict__ featr,
                   const float* __restrict__ gc, _Float16* __restrict__ oh,
                   _Float16* __restrict__ ol)
{
  int row = blockIdx.x;           // 25600
  float g = gc[row];
  for (int j = threadIdx.x; j < 544; j += 256){
    float v = 0.f;
    if (j < 512)      v = RmD[(long)row*512 + j]*g;
    else if (j < 514) v = featr[(long)row*2 + (j-512)]*g;
    _Float16 h = (_Float16)v;
    oh[(long)row*544 + j] = h;
    ol[(long)row*544 + j] = (_Float16)(v - (float)h);
  }
}

__global__ __launch_bounds__(256)
void k_maxt2(const float* __restrict__ hs0, float* __restrict__ o0, int S0, int T0,
             const float* __restrict__ hs1, float* __restrict__ o1, int T1)
{
  int x = blockIdx.x; int d = threadIdx.x;
  const float* hs; float* op; int T, s;
  if (x < S0){ hs = hs0; op = o0; T = T0; s = x; }
  else       { hs = hs1; op = o1; T = T1; s = x - S0; }
  float m = -3.4e38f;
  for (int t = 0; t < T; ++t) m = fmaxf(m, hs[((long)s*T + t)*256 + d]);
  op[s*256 + d] = m;
}

__global__ __launch_bounds__(512)
void k_final(const float* __restrict__ q_out, const float* __restrict__ c_out,
             const float* __restrict__ gnW, const float* __restrict__ gnB,
             const float* __restrict__ decW, const float* __restrict__ decB,
             const float* __restrict__ logics, float* __restrict__ out)
{
  int b = blockIdx.x;
  int t = threadIdx.x;
  __shared__ float red[512];
  float mx = -3.4e38f, sm = 0.f;
  for (int n = 0; n < 10; ++n) {
    int s = b*10 + n;
    float f = (t < 256) ? q_out[(long)s*256 + t] : c_out[(long)s*256 + (t-256)];
    red[t] = f * gnW[t]; __syncthreads();
    for (int st=256; st; st>>=1){ if (t<st) red[t]+=red[t+st]; __syncthreads(); }
    float g = sigf(red[0] + gnB[0]);
    __syncthreads();
    float gf = f*g;
    mx = fmaxf(mx, gf); sm += gf;
  }
  sm *= 0.1f;
  red[t] = mx*decW[t] + sm*decW[512 + t]; __syncthreads();
  for (int st=256; st; st>>=1){ if (t<st) red[t]+=red[t+st]; __syncthreads(); }
  if (t == 0) out[b] = (red[0] + decB[0]) * logics[b];
}

static inline int cdiv(int a, int b){ return (a + b - 1)/b; }

extern "C" void kernel_launch(void* const* d_in, const int* in_sizes, int n_in,
                              void* d_out, int out_size, void* d_ws, size_t ws_size,
                              hipStream_t stream)
{
  const int*   contents = (const int*)  d_in[0];
  const int*   qa       = (const int*)  d_in[1];
  const float* logics   = (const float*)d_in[2];
  const float* ef       = (const float*)d_in[3];
  const float* ed       = (const float*)d_in[4];
  const float* ctx_Wi   = (const float*)d_in[5];
  const float* ctx_Wh   = (const float*)d_in[6];
  const float* ctx_b    = (const float*)d_in[7];
  const float* qr_Wi    = (const float*)d_in[8];
  const float* qr_Wh    = (const float*)d_in[9];
  const float* qr_b     = (const float*)d_in[10];
  const float* cr_Wi    = (const float*)d_in[11];
  const float* cr_Wh    = (const float*)d_in[12];
  const float* cr_b     = (const float*)d_in[13];
  const float* grW      = (const float*)d_in[14];
  const float* grB      = (const float*)d_in[15];
  const float* gnW      = (const float*)d_in[16];
  const float* gnB      = (const float*)d_in[17];
  const float* decW     = (const float*)d_in[18];
  const float* decB     = (const float*)d_in[19];
  float* out = (float*)d_out;
  float* w = (float*)d_ws;

  const long RU = 26624;                    // unified embed/proj rows (208*128)
  size_t o = 0;
  auto alloc = [&](size_t n){ size_t r = o; o += (n + 63) & ~(size_t)63; return r; };
  size_t cv16    = alloc((size_t)RU*224);   // dead after ctx proj
  size_t ctxW16  = alloc(1024u*224);
  size_t qrW16   = alloc(1024u*288);
  size_t crW16   = alloc(1024u*544);
  size_t c_xg    = alloc((size_t)RU*1024);  // rows 25600.. = q_xg; reused attn fp16 + cr_xg
  size_t q_enc   = alloc(1000u*256);
  size_t D_enc   = alloc(25600u*256);
  size_t gate_q  = alloc(1000);
  size_t gate_c  = alloc(25600);
  size_t M_qc    = alloc(2560000);
  size_t an_     = alloc(2560000);          // an fp16 hi/lo overlay
  size_t bn_     = alloc(3276800);          // bnT fp16 hi/lo [100][256][128]
  size_t featc   = alloc(20000);
  size_t featr   = alloc(51200);
  size_t RnQ     = alloc(2560000);
  size_t Xb      = alloc(10u*2560*512);
  size_t Sbuf    = alloc(6553600);          // D16t overlay pre-attention
  size_t RmD     = alloc(10u*2560*512);     // D16 overlay pre-attention; PV out
  size_t rnq16   = alloc(10000u*288);
  size_t qr_xg   = alloc(10000u*1024);      // S fp16 slab pool during attention...
  size_t q_hs    = alloc(100u*100*256);     // ...contiguous: qr_xg,q_hs,rmd16,c_hs
  size_t rmd16   = alloc(25600u*544);
  size_t c_hs    = alloc(100u*256*256);
  size_t q_out   = alloc(100u*256);
  size_t c_out   = alloc(100u*256);

  if (ws_size < o*sizeof(float)) {
    k_sentinel<<<1,64,0,stream>>>(out, out_size);
    return;
  }

  // fp16 views
  _Float16* cvh = (_Float16*)(w + cv16);       _Float16* cvl = cvh + RU*224;
  _Float16* cWh = (_Float16*)(w + ctxW16);     _Float16* cWl = cWh + 1024L*224;
  _Float16* qWh = (_Float16*)(w + qrW16);      _Float16* qWl = qWh + 1024L*288;
  _Float16* rWh = (_Float16*)(w + crW16);      _Float16* rWl = rWh + 1024L*544;
  _Float16* nqh = (_Float16*)(w + rnq16);      _Float16* nql = nqh + 10000L*288;
  _Float16* mdh = (_Float16*)(w + rmd16);      _Float16* mdl = mdh + 25600L*544;
  // attention overlays (dead-region reuse)
  _Float16* Xh  = (_Float16*)(w + c_xg);       // 4 x 13,107,200 halves <= c_xg
  _Float16* Xl  = Xh  + 13107200L;
  _Float16* Xth = Xl  + 13107200L;
  _Float16* Xtl = Xth + 13107200L;
  // S fp16 slab pool (5 b's at a time): contiguous dead run qr_xg..c_hs
  // = 33,280,000 floats = 66,560,000 halves >= 2*5*6,553,600 = 65,536,000
  _Float16* ShA = (_Float16*)(w + qr_xg);
  _Float16* SlA = ShA + 5L*6553600L;
  // pre-attention fp16 overlays
  _Float16* anh = (_Float16*)(w + an_);        _Float16* anl = anh + 2560000L;
  _Float16* bth = (_Float16*)(w + bn_);        _Float16* btl = bth + 3276800L;
  _Float16* D16h = (_Float16*)(w + RmD);       _Float16* D16l = D16h + 6553600L;   // row-major
  _Float16* Dt16h = (_Float16*)(w + Sbuf);     _Float16* Dt16l = Dt16h + 6553600L; // transposed
  _Float16* q16h = (_Float16*)(w + q_hs);      _Float16* q16l = q16h + 256000L;
  _Float16* qt16h = q16l + 256000L;            _Float16* qt16l = qt16h + 327680L;  // [b][256][128]
  float* q_xg_p = w + c_xg + 25600L*1024;

  // --- weight transforms + unified embeddings ---
  k_wsplit<<<1024,256,0,stream>>>(ctx_Wi, cWh, cWl, 200, 224);
  k_wsplit<<<1024,256,0,stream>>>(qr_Wi,  qWh, qWl, 258, 288);
  k_wsplit<<<1024,256,0,stream>>>(cr_Wi,  rWh, rWl, 514, 544);
  k_embed16u<<<(int)RU, 256, 0, stream>>>(contents, qa, ef, ed, cvh, cvl, 224);

  // --- ctx input projection (content + question, one dispatch) ---
  k_mfma<<<dim3(208,8,1),256,0,stream>>>(cvh, cvl, cWh, cWl, w+c_xg,
      (int)RU, 224, 1024, 1024, 0L,0L,0L, 1,1, 3, nullptr, nullptr, 0L);

  // --- ctx LSTMs (content T=256 + question T=100, one dispatch) ---
  k_lstm2<<<dim3(110,2),512,0,stream>>>(
      w+c_xg, ctx_Wh, ctx_b, w+D_enc, 100, 256, 1024,
      q_xg_p, ctx_Wh, ctx_b, w+q_enc, 100, 1024);

  // --- reasoning gates ---
  k_gate<<<cdiv(1000,4),256,0,stream>>>(w+q_enc, grW, grB, w+gate_q, 1000);
  k_gate<<<cdiv(25600,4),256,0,stream>>>(w+D_enc, grW, grB, w+gate_c, 25600);

  // --- fp16 operand prep for matching GEMMs ---
  k_split_hl<<<cdiv(6553600,256),256,0,stream>>>(w+D_enc, D16h, D16l, 6553600L);
  k_split_hl<<<cdiv(256000,256),256,0,stream>>>(w+q_enc, q16h, q16l, 256000L);
  k_transp_hl<<<dim3(8,8,100),256,0,stream>>>(w+D_enc, Dt16h, Dt16l, 256, 256, 65536L, 65536L);
  k_transp_hl<<<dim3(4,8,10),256,0,stream>>>(w+q_enc, qt16h, qt16l, 100, 128, 25600L, 32768L);

  // --- M_qc[bn] = q_enc[b] @ D_enc[bn]^T  (MFMA, z=100) ---
  k_mfma<<<dim3(1,2,100),256,0,stream>>>(q16h, q16l, D16h, D16l, w+M_qc,
      100, 256, 256, 256, 25600L, 65536L, 25600L, 10, 1, 3, nullptr, nullptr, 0L);

  // --- softmaxes + feats (emit fp16 splits directly) ---
  k_an_feat16<<<10000,256,0,stream>>>(w+M_qc, anh, anl, w+featc);
  k_bn_feat16<<<100,1024,0,stream>>>(w+M_qc, bth, btl, w+featr);

  // --- RnQ = an @ D_enc ---
  k_mfma<<<dim3(1,2,100),256,0,stream>>>(anh, anl, Dt16h, Dt16l, w+RnQ,
      100, 256, 256, 256, 25600L, 65536L, 25600L, 1, 1, 3, nullptr, nullptr, 0L);

  // --- RnD = bn^T @ q_enc -> X[...,256:512] ---
  k_mfma<<<dim3(2,2,100),256,0,stream>>>(bth, btl, qt16h, qt16l, w+Xb+256,
      256, 128, 256, 512, 32768L, 32768L, 131072L, 1, 10, 3, nullptr, nullptr, 0L);

  // --- X[...,0:256] = D_enc ---
  k_copy_to_x<<<25600,256,0,stream>>>(w+D_enc, w+Xb);

  // --- fp16 splits of X (row-major and transposed) ---
  k_split_hl<<<51200,256,0,stream>>>(w+Xb, Xh, Xl, 13107200L);
  k_transpose_hl<<<dim3(80,16,10),256,0,stream>>>(w+Xb, Xth, Xtl);

  // --- cross-doc attention, 5 b's per macro-iteration, fp16-S pipeline ---
  for (int half = 0; half < 2; ++half) {
    const long xo = (long)half*5*1310720;
    // QK: S = X@X^T, 2-pass, write fp16 hi/lo slabs directly
    k_mfma<<<dim3(20,20,5),256,0,stream>>>(Xh+xo, Xl+xo, Xh+xo, Xl+xo, nullptr,
        2560, 512, 2560, 2560, 1310720L, 1310720L, 0L, 1, 1, 2, ShA, SlA, 6553600L);
    // in-place fp16 softmax
    k_softmax2560_io16<<<dim3(2560,5),256,0,stream>>>(ShA, SlA, 6553600L);
    // PV: RmD = S@X (B = pre-transposed Xt), 2-pass
    k_mfma<<<dim3(20,4,5),256,0,stream>>>(ShA, SlA, Xth+xo, Xtl+xo, w+RmD+xo,
        2560, 2560, 512, 512, 6553600L, 1310720L, 1310720L, 1, 1, 2,
        nullptr, nullptr, 0L);
  }

  // --- qr + cr input builds and projections ---
  k_build_rnq16<<<10000,320,0,stream>>>(w+RnQ, w+featc, w+gate_q, nqh, nql);
  k_mfma<<<dim3(79,8,1),256,0,stream>>>(nqh, nql, qWh, qWl, w+qr_xg,
      10000, 288, 1024, 1024, 0L,0L,0L, 1,1, 3, nullptr, nullptr, 0L);
  k_build_rmd16<<<25600,256,0,stream>>>(w+RmD, w+featr, w+gate_c, mdh, mdl);
  k_mfma<<<dim3(200,8,1),256,0,stream>>>(mdh, mdl, rWh, rWl, w+c_xg,
      25600, 544, 1024, 1024, 0L,0L,0L, 1,1, 3, nullptr, nullptr, 0L);

  // --- qr + cr LSTMs in one dispatch ---
  k_lstm2<<<dim3(200,2),512,0,stream>>>(
      w+c_xg, cr_Wh, cr_b, w+c_hs, 100, 256, 1024,
      w+qr_xg, qr_Wh, qr_b, w+q_hs, 100, 1024);

  // --- max over time ---
  k_maxt2<<<200,256,0,stream>>>(w+c_hs, w+c_out, 100, 256, w+q_hs, w+q_out, 100);

  // --- decode head ---
  k_final<<<10,512,0,stream>>>(w+q_out, w+c_out, gnW, gnB, decW, decB, logics, out);
}

// Round 14
// 1845.639 us; speedup vs baseline: 1.4333x; 1.0152x over previous
//
#include <hip/hip_runtime.h>
#include <cstdint>
#include <cstddef>

typedef __attribute__((ext_vector_type(8))) _Float16 half8;
typedef __attribute__((ext_vector_type(4))) float f32x4;

__device__ __forceinline__ float fexp(float x){ return __expf(x); }
__device__ __forceinline__ float sig_fast(float x){
  return __builtin_amdgcn_rcpf(1.f + __expf(-x));
}
__device__ __forceinline__ float tanh_fast(float x){
  return 2.f*__builtin_amdgcn_rcpf(1.f + __expf(-2.f*x)) - 1.f;
}
__device__ __forceinline__ float sigf(float x){ return 1.0f/(1.0f+expf(-x)); }

__device__ __forceinline__ void async_lds16(const _Float16* g, _Float16* l){
  __builtin_amdgcn_global_load_lds(
      (const __attribute__((address_space(1))) void*)g,
      (__attribute__((address_space(3))) void*)l, 16, 0, 0);
}

__global__ __launch_bounds__(64)
void k_sentinel(float* out, int n){ int i=threadIdx.x; if(i<n) out[i]=1.0e9f; }

// f32 -> fp16 cast (same layout)
__global__ __launch_bounds__(256)
void k_cvt16(const float* __restrict__ src, _Float16* __restrict__ dst, int n)
{
  int i = blockIdx.x*256 + threadIdx.x;
  if (i < n) dst[i] = (_Float16)src[i];
}

// unified embeddings: rows 0..25599 = contents, 25600..26599 = question, rest zero
__global__ __launch_bounds__(256)
void k_embed16u(const int* __restrict__ c_tok, const int* __restrict__ q_tok,
                const float* __restrict__ ef, const float* __restrict__ ed,
                _Float16* __restrict__ oh, _Float16* __restrict__ ol, int Kpad)
{
  int t = blockIdx.x; int e = threadIdx.x;
  if (e >= Kpad) return;
  _Float16 h = (_Float16)0.f, l = (_Float16)0.f;
  int tok = -1;
  if (t < 25600) tok = c_tok[t];
  else if (t < 26600) tok = q_tok[t - 25600];
  if (tok >= 0 && e < 200){
    long r = (long)tok*200 + e;
    float v = ef[r] + ed[r];
    h = (_Float16)v; l = (_Float16)(v - (float)h);
  }
  oh[(long)t*Kpad + e] = h;
  ol[(long)t*Kpad + e] = l;
}

// W[2][K][512] -> Wt_h/Wt_l[(dir*512+n)][Kpad]
__global__ __launch_bounds__(256)
void k_wsplit(const float* __restrict__ W, _Float16* __restrict__ th,
              _Float16* __restrict__ tl, int K, int Kpad)
{
  int n = blockIdx.x;               // 0..1023
  int dir = n >> 9, col = n & 511;
  for (int k = threadIdx.x; k < Kpad; k += 256){
    _Float16 h = (_Float16)0.f, l = (_Float16)0.f;
    if (k < K){
      float v = W[((long)dir*K + k)*512 + col];
      h = (_Float16)v; l = (_Float16)(v - (float)h);
    }
    th[(long)n*Kpad + k] = h;
    tl[(long)n*Kpad + k] = l;
  }
}

// ---------------- split-fp16 MFMA GEMM, z-batched, 2/3-pass, f32 or fp16 out --
#define MFMA16(a,b,c) __builtin_amdgcn_mfma_f32_16x16x32_f16(a,b,c,0,0,0)

__global__ __launch_bounds__(256, 2)
void k_mfma(const _Float16* __restrict__ Ahb, const _Float16* __restrict__ Alb,
            const _Float16* __restrict__ Bhb, const _Float16* __restrict__ Blb,
            float* __restrict__ Cb, int M, int K, int N, int ldc,
            long sA, long sB, long sC, int divA, int divB, int passes,
            _Float16* __restrict__ Chb, _Float16* __restrict__ Clb, long sCh)
{
  const int z = blockIdx.z;
  const _Float16* Ah = Ahb + (long)(z/divA)*sA;
  const _Float16* Al = Alb + (long)(z/divA)*sA;
  const _Float16* Bh = Bhb + (long)(z/divB)*sB;
  const _Float16* Bl = Blb + (long)(z/divB)*sB;

  const int m0 = blockIdx.x*128, n0 = blockIdx.y*128;
  const int tid = threadIdx.x;
  const int lane = tid & 63, wave = tid >> 6;
  const int wm = wave >> 1, wn = wave & 1;     // 2x2 waves, 64x64 per wave

  __shared__ _Float16 lds[2][2048*8];

  f32x4 acc[4][4] = {};

  const int KT = K >> 5;
  const bool p3 = (passes == 3);

  auto STAGE = [&](int buf, int kt){
    const int k0 = kt*32;
    #pragma unroll
    for (int it = 0; it < 8; ++it){
      const int c  = it*256 + tid;
      const int op = it >> 1;
      if (!p3 && op == 1) continue;          // Al unused in 2-pass: skip staging
      const int kb = (c >> 7) & 3;
      const int row = c & 127;
      const _Float16* base = (op==0) ? Ah : (op==1) ? Al : (op==2) ? Bh : Bl;
      int gr = (op < 2) ? (m0 + row) : (n0 + row);
      if (op < 2 && gr >= M) gr = M - 1;
      const _Float16* src = base + (long)gr*K + k0 + kb*8;
      _Float16* dst = &lds[buf][(size_t)(it*256 + (tid & ~63))*8];
      async_lds16(src, dst);
    }
  };

  auto COMPUTE = [&](int buf){
    const int kb = lane >> 4, r = lane & 15;
    half8 ah[4], al[4], bh[4], bl[4];
    #pragma unroll
    for (int mi = 0; mi < 4; ++mi){
      ah[mi] = *(const half8*)&lds[buf][(size_t)(        kb*128 + wm*64 + mi*16 + r)*8];
      if (p3) al[mi] = *(const half8*)&lds[buf][(size_t)( 512 + kb*128 + wm*64 + mi*16 + r)*8];
    }
    #pragma unroll
    for (int ni = 0; ni < 4; ++ni){
      bh[ni] = *(const half8*)&lds[buf][(size_t)(1024 + kb*128 + wn*64 + ni*16 + r)*8];
      bl[ni] = *(const half8*)&lds[buf][(size_t)(1536 + kb*128 + wn*64 + ni*16 + r)*8];
    }
    #pragma unroll
    for (int mi = 0; mi < 4; ++mi)
      #pragma unroll
      for (int ni = 0; ni < 4; ++ni){
        acc[mi][ni] = MFMA16(ah[mi], bh[ni], acc[mi][ni]);
        acc[mi][ni] = MFMA16(ah[mi], bl[ni], acc[mi][ni]);
        if (p3) acc[mi][ni] = MFMA16(al[mi], bh[ni], acc[mi][ni]);
      }
  };

  STAGE(0, 0);
  for (int kt = 0; kt < KT; ++kt){
    __syncthreads();
    if (kt + 1 < KT) STAGE((kt+1)&1, kt+1);
    COMPUTE(kt&1);
  }

  const int r4 = (lane >> 4) * 4, cN = lane & 15;
  if (Chb){
    _Float16* Ch = Chb + (long)z*sCh;
    _Float16* Cl = Clb + (long)z*sCh;
    #pragma unroll
    for (int mi = 0; mi < 4; ++mi)
      #pragma unroll
      for (int ni = 0; ni < 4; ++ni){
        const int row = m0 + wm*64 + mi*16 + r4;
        const int col = n0 + wn*64 + ni*16 + cN;
        #pragma unroll
        for (int r = 0; r < 4; ++r)
          if (row + r < M){
            float v = acc[mi][ni][r];
            _Float16 hh = (_Float16)v;
            long idx = (long)(row + r)*ldc + col;
            Ch[idx] = hh;
            Cl[idx] = (_Float16)(v - (float)hh);
          }
      }
  } else {
    float* C = Cb + (long)z*sC;
    #pragma unroll
    for (int mi = 0; mi < 4; ++mi)
      #pragma unroll
      for (int ni = 0; ni < 4; ++ni){
        const int row = m0 + wm*64 + mi*16 + r4;
        const int col = n0 + wn*64 + ni*16 + cN;
        #pragma unroll
        for (int r = 0; r < 4; ++r)
          if (row + r < M) C[(long)(row + r)*ldc + col] = acc[mi][ni][r];
      }
  }
}

// ---------------- merged 2-job LSTM scan, fp16 recurrent weights -------------
// L2-BW bound at 256KB f32 weights/block/step (= measured 34.3 TB/s aggregate,
// R13). fp16 weights halve the streamed bytes; v_fma_mix keeps VALU count flat.
__global__ __launch_bounds__(512, 1)
void k_lstm2(const float* __restrict__ xg0, const _Float16* __restrict__ Wh0,
             const float* __restrict__ bs0, float* __restrict__ out0,
             int S0, int T0, int ldx0,
             const float* __restrict__ xg1, const _Float16* __restrict__ Wh1,
             const float* __restrict__ bs1, float* __restrict__ out1,
             int T1, int ldx1)
{
  const int bx = blockIdx.x;
  const int dir = blockIdx.y;
  const float* xg; const _Float16* Whb; const float* bsb; float* out;
  int T, ldx, s;
  if (bx < S0){ s = bx;      xg = xg0; Whb = Wh0; bsb = bs0; out = out0; T = T0; ldx = ldx0; }
  else        { s = bx - S0; xg = xg1; Whb = Wh1; bsb = bs1; out = out1; T = T1; ldx = ldx1; }
  xg += dir*512;
  const _Float16* Wp = Whb + (long)dir*128*512 + threadIdx.x;
  const int dirOff = dir*128;
  const int k = threadIdx.x;
  const float bv = bsb[dir*512 + k];

  __shared__ __align__(16) float h_lds[128];
  __shared__ float a_lds[512];
  float c = 0.f;
  if (k < 128) h_lds[k] = 0.f;
  __syncthreads();

  float gcur = xg[((long)s*T + (dir ? T-1 : 0))*ldx + k];

  for (int tt = 0; tt < T; ++tt) {
    const int t = dir ? (T-1-tt) : tt;
    float gnext = 0.f;
    if (tt + 1 < T){
      const int tn = dir ? (T-2-tt) : (tt+1);
      gnext = xg[((long)s*T + tn)*ldx + k];
    }
    float acc0 = gcur + bv, acc1 = 0.f, acc2 = 0.f, acc3 = 0.f;
    #pragma unroll
    for (int m = 0; m < 32; ++m) {
      float4 h4 = *(const float4*)&h_lds[m*4];
      acc0 += h4.x * (float)Wp[(m*4+0)*512];
      acc1 += h4.y * (float)Wp[(m*4+1)*512];
      acc2 += h4.z * (float)Wp[(m*4+2)*512];
      acc3 += h4.w * (float)Wp[(m*4+3)*512];
    }
    float g = (acc0 + acc1) + (acc2 + acc3);
    a_lds[k] = ((k >> 7) == 2) ? tanh_fast(g) : sig_fast(g);
    __syncthreads();
    if (k < 128) {
      float ig = a_lds[k];
      float fg = a_lds[k+128];
      float gg = a_lds[k+256];
      float og = a_lds[k+384];
      c = fg*c + ig*gg;
      float h = og*tanh_fast(c);
      h_lds[k] = h;
      out[((long)s*T + t)*256 + dirOff + k] = h;
    }
    __syncthreads();
    gcur = gnext;
  }
}

__global__ __launch_bounds__(256)
void k_gate(const float* __restrict__ in, const float* __restrict__ w,
            const float* __restrict__ b, float* __restrict__ out, int R)
{
  int row = blockIdx.x*4 + (threadIdx.x >> 6);
  int lane = threadIdx.x & 63;
  if (row >= R) return;
  const float* p = in + (long)row*256;
  float s = 0.f;
  #pragma unroll
  for (int j = 0; j < 4; ++j) s += p[lane + j*64]*w[lane + j*64];
  #pragma unroll
  for (int off = 32; off; off >>= 1) s += __shfl_down(s, off);
  if (lane == 0) out[row] = sigf(s + b[0]) + 1e-8f;
}

// an row-softmax -> fp16 hi/lo; feat_col = {max, mean}; shfl-based reductions
__global__ __launch_bounds__(256)
void k_an_feat16(const float* __restrict__ Mq, _Float16* __restrict__ anh,
                 _Float16* __restrict__ anl, float* __restrict__ feat)
{
  long r = blockIdx.x;
  int t = threadIdx.x;
  const int wid = t >> 6, lane = t & 63;
  float v = Mq[r*256 + t];
  float mx = v, sv = v;
  #pragma unroll
  for (int off = 32; off; off >>= 1){
    mx = fmaxf(mx, __shfl_down(mx, off));
    sv += __shfl_down(sv, off);
  }
  __shared__ float wmx[4], wsv[4], wse[4];
  if (lane == 0){ wmx[wid] = mx; wsv[wid] = sv; }
  __syncthreads();
  mx = fmaxf(fmaxf(wmx[0],wmx[1]), fmaxf(wmx[2],wmx[3]));
  sv = (wsv[0]+wsv[1]) + (wsv[2]+wsv[3]);
  float e = fexp(v - mx);
  float se = e;
  #pragma unroll
  for (int off = 32; off; off >>= 1) se += __shfl_down(se, off);
  if (lane == 0) wse[wid] = se;
  __syncthreads();
  se = (wse[0]+wse[1]) + (wse[2]+wse[3]);
  float a = e / se;
  _Float16 h = (_Float16)a;
  anh[r*256 + t] = h;
  anl[r*256 + t] = (_Float16)(a - (float)h);
  if (t == 0){ feat[r*2] = mx; feat[r*2+1] = sv*(1.f/256.f); }
}

// bn softmax over q -> TRANSPOSED fp16 hi/lo [bn][l=256][q padded 128]; feat_row
__global__ __launch_bounds__(1024)
void k_bn_feat16(const float* __restrict__ Mq, _Float16* __restrict__ bth,
                 _Float16* __restrict__ btl, float* __restrict__ feat)
{
  int bn = blockIdx.x;
  int t = threadIdx.x;
  int l = t & 255, qg = t >> 8;
  const float* Mb = Mq + (long)bn*25600;
  const int q0 = qg*25, q1 = q0 + 25;
  float mx = -3.4e38f, sv = 0.f;
  for (int q = q0; q < q1; ++q){ float v = Mb[q*256 + l]; mx = fmaxf(mx, v); sv += v; }
  __shared__ float smx[4][256], ssv[4][256], sse[4][256];
  smx[qg][l] = mx; ssv[qg][l] = sv;
  __syncthreads();
  mx = fmaxf(fmaxf(smx[0][l],smx[1][l]), fmaxf(smx[2][l],smx[3][l]));
  sv = (ssv[0][l]+ssv[1][l]) + (ssv[2][l]+ssv[3][l]);
  float se = 0.f;
  for (int q = q0; q < q1; ++q) se += fexp(Mb[q*256 + l] - mx);
  sse[qg][l] = se;
  __syncthreads();
  se = (sse[0][l]+sse[1][l]) + (sse[2][l]+sse[3][l]);
  float inv = 1.f/se;
  long base = ((long)bn*256 + l)*128;
  for (int q = q0; q < q1; ++q){
    float a = fexp(Mb[q*256 + l] - mx)*inv;
    _Float16 h = (_Float16)a;
    bth[base + q] = h;
    btl[base + q] = (_Float16)(a - (float)h);
  }
  if (qg == 0){
    for (int q = 100; q < 128; ++q){ bth[base+q] = (_Float16)0.f; btl[base+q] = (_Float16)0.f; }
    long fr = (long)(bn*256 + l)*2;
    feat[fr] = mx; feat[fr+1] = sv*0.01f;
  }
}

__global__ __launch_bounds__(256)
void k_copy_to_x(const float* __restrict__ D, float* __restrict__ X)
{
  long idx = (long)blockIdx.x*256 + threadIdx.x;
  long r = idx >> 8; int d = idx & 255;
  X[r*512 + d] = D[idx];
}

__global__ __launch_bounds__(256)
void k_split_hl(const float* __restrict__ x, _Float16* __restrict__ h,
                _Float16* __restrict__ l, long n)
{
  long i = (long)blockIdx.x*256 + threadIdx.x;
  if (i >= n) return;
  float v = x[i];
  _Float16 hi = (_Float16)v;
  h[i] = hi;
  l[i] = (_Float16)(v - (float)hi);
}

// generic batched transpose+split
__global__ __launch_bounds__(256)
void k_transp_hl(const float* __restrict__ src, _Float16* __restrict__ th,
                 _Float16* __restrict__ tl, int R, int Kp, long sSrc, long sDst)
{
  __shared__ float tile[32][33];
  const int m0 = blockIdx.x*32, n0 = blockIdx.y*32, z = blockIdx.z;
  const float* S = src + (long)z*sSrc;
  const int tx = threadIdx.x & 31, ty = threadIdx.x >> 5;
  #pragma unroll
  for (int r = 0; r < 32; r += 8){
    int gr = m0 + ty + r;
    tile[ty+r][tx] = (gr < R) ? S[(long)gr*256 + n0 + tx] : 0.f;
  }
  __syncthreads();
  const long base = (long)z*sDst;
  #pragma unroll
  for (int r = 0; r < 32; r += 8){
    float v = tile[tx][ty+r];
    _Float16 h = (_Float16)v;
    long o2 = base + (long)(n0+ty+r)*Kp + m0+tx;
    th[o2] = h;
    tl[o2] = (_Float16)(v - (float)h);
  }
}

// per-b X transpose (2560x512 -> 512x2560), split
__global__ __launch_bounds__(256)
void k_transpose_hl(const float* __restrict__ X, _Float16* __restrict__ Th,
                    _Float16* __restrict__ Tl)
{
  __shared__ float tile[32][33];
  const int m0 = blockIdx.x*32, n0 = blockIdx.y*32, b = blockIdx.z;
  const float* Xb = X + (long)b*2560*512;
  const int tx = threadIdx.x & 31, ty = threadIdx.x >> 5;
  #pragma unroll
  for (int r = 0; r < 32; r += 8)
    tile[ty+r][tx] = Xb[(long)(m0+ty+r)*512 + n0+tx];
  __syncthreads();
  const long base = (long)b*512*2560;
  #pragma unroll
  for (int r = 0; r < 32; r += 8){
    float v = tile[tx][ty+r];
    _Float16 h = (_Float16)v;
    long o2 = base + (long)(n0+ty+r)*2560 + m0+tx;
    Th[o2] = h;
    Tl[o2] = (_Float16)(v - (float)h);
  }
}

// z-batched IN-PLACE row softmax on fp16 hi/lo S slabs (v = hi + lo)
__global__ __launch_bounds__(256)
void k_softmax2560_io16(_Float16* __restrict__ ShA, _Float16* __restrict__ SlA,
                        long slab)
{
  const int z = blockIdx.y;
  _Float16* Sh = ShA + (long)z*slab;
  _Float16* Sl = SlA + (long)z*slab;
  long r = blockIdx.x;
  int t = threadIdx.x;
  float loc[10];
  float mx = -3.4e38f;
  #pragma unroll
  for (int i=0;i<10;++i){
    long idx = r*2560 + t + i*256;
    loc[i] = (float)Sh[idx] + (float)Sl[idx];
    mx = fmaxf(mx, loc[i]);
  }
  __shared__ float red[256];
  red[t]=mx; __syncthreads();
  for (int s2=128;s2;s2>>=1){ if(t<s2) red[t]=fmaxf(red[t],red[t+s2]); __syncthreads(); }
  mx = red[0]; __syncthreads();
  float se=0.f;
  #pragma unroll
  for (int i=0;i<10;++i){ loc[i]=fexp(loc[i]-mx); se+=loc[i]; }
  red[t]=se; __syncthreads();
  for (int s2=128;s2;s2>>=1){ if(t<s2) red[t]+=red[t+s2]; __syncthreads(); }
  float inv = 1.f/red[0];
  #pragma unroll
  for (int i=0;i<10;++i){
    float v = loc[i]*inv;
    _Float16 h = (_Float16)v;
    long idx = r*2560 + t + i*256;
    Sh[idx] = h;
    Sl[idx] = (_Float16)(v - (float)h);
  }
}

// RnQ_in hi/lo fp16, K padded 258->288
__global__ __launch_bounds__(320)
void k_build_rnq16(const float* __restrict__ RnQ, const float* __restrict__ featc,
                   const float* __restrict__ gq, _Float16* __restrict__ oh,
                   _Float16* __restrict__ ol)
{
  int row = blockIdx.x;           // 10000
  int t = threadIdx.x;
  if (t >= 288) return;
  int b = row / 1000, q = row % 100;
  float g = gq[b*100 + q];
  float v = 0.f;
  if (t < 256)      v = RnQ[(long)row*256 + t]*g;
  else if (t < 258) v = featc[(long)row*2 + (t-256)]*g;
  _Float16 h = (_Float16)v;
  oh[(long)row*288 + t] = h;
  ol[(long)row*288 + t] = (_Float16)(v - (float)h);
}

// RmD_in hi/lo fp16, K padded 514->544
__global__ __launch_bounds__(256)
void k_build_rmd16(const float* __restrict__ RmD, const float* __restrict__ featr,
                   const float* __restrict__ gc, _Float16* __restrict__ oh,
                   _Float16* __restrict__ ol)
{
  int row = blockIdx.x;           // 25600
  float g = gc[row];
  for (int j = threadIdx.x; j < 544; j += 256){
    float v = 0.f;
    if (j < 512)      v = RmD[(long)row*512 + j]*g;
    else if (j < 514) v = featr[(long)row*2 + (j-512)]*g;
    _Float16 h = (_Float16)v;
    oh[(long)row*544 + j] = h;
    ol[(long)row*544 + j] = (_Float16)(v - (float)h);
  }
}

__global__ __launch_bounds__(256)
void k_maxt2(const float* __restrict__ hs0, float* __restrict__ o0, int S0, int T0,
             const float* __restrict__ hs1, float* __restrict__ o1, int T1)
{
  int x = blockIdx.x; int d = threadIdx.x;
  const float* hs; float* op; int T, s;
  if (x < S0){ hs = hs0; op = o0; T = T0; s = x; }
  else       { hs = hs1; op = o1; T = T1; s = x - S0; }
  float m = -3.4e38f;
  for (int t = 0; t < T; ++t) m = fmaxf(m, hs[((long)s*T + t)*256 + d]);
  op[s*256 + d] = m;
}

__global__ __launch_bounds__(512)
void k_final(const float* __restrict__ q_out, const float* __restrict__ c_out,
             const float* __restrict__ gnW, const float* __restrict__ gnB,
             const float* __restrict__ decW, const float* __restrict__ decB,
             const float* __restrict__ logics, float* __restrict__ out)
{
  int b = blockIdx.x;
  int t = threadIdx.x;
  __shared__ float red[512];
  float mx = -3.4e38f, sm = 0.f;
  for (int n = 0; n < 10; ++n) {
    int s = b*10 + n;
    float f = (t < 256) ? q_out[(long)s*256 + t] : c_out[(long)s*256 + (t-256)];
    red[t] = f * gnW[t]; __syncthreads();
    for (int st=256; st; st>>=1){ if (t<st) red[t]+=red[t+st]; __syncthreads(); }
    float g = sigf(red[0] + gnB[0]);
    __syncthreads();
    float gf = f*g;
    mx = fmaxf(mx, gf); sm += gf;
  }
  sm *= 0.1f;
  red[t] = mx*decW[t] + sm*decW[512 + t]; __syncthreads();
  for (int st=256; st; st>>=1){ if (t<st) red[t]+=red[t+st]; __syncthreads(); }
  if (t == 0) out[b] = (red[0] + decB[0]) * logics[b];
}

static inline int cdiv(int a, int b){ return (a + b - 1)/b; }

extern "C" void kernel_launch(void* const* d_in, const int* in_sizes, int n_in,
                              void* d_out, int out_size, void* d_ws, size_t ws_size,
                              hipStream_t stream)
{
  const int*   contents = (const int*)  d_in[0];
  const int*   qa       = (const int*)  d_in[1];
  const float* logics   = (const float*)d_in[2];
  const float* ef       = (const float*)d_in[3];
  const float* ed       = (const float*)d_in[4];
  const float* ctx_Wi   = (const float*)d_in[5];
  const float* ctx_Wh   = (const float*)d_in[6];
  const float* ctx_b    = (const float*)d_in[7];
  const float* qr_Wi    = (const float*)d_in[8];
  const float* qr_Wh    = (const float*)d_in[9];
  const float* qr_b     = (const float*)d_in[10];
  const float* cr_Wi    = (const float*)d_in[11];
  const float* cr_Wh    = (const float*)d_in[12];
  const float* cr_b     = (const float*)d_in[13];
  const float* grW      = (const float*)d_in[14];
  const float* grB      = (const float*)d_in[15];
  const float* gnW      = (const float*)d_in[16];
  const float* gnB      = (const float*)d_in[17];
  const float* decW     = (const float*)d_in[18];
  const float* decB     = (const float*)d_in[19];
  float* out = (float*)d_out;
  float* w = (float*)d_ws;

  const long RU = 26624;                    // unified embed/proj rows (208*128)
  size_t o = 0;
  auto alloc = [&](size_t n){ size_t r = o; o += (n + 63) & ~(size_t)63; return r; };
  size_t cv16    = alloc((size_t)RU*224);   // dead after ctx proj
  size_t ctxW16  = alloc(1024u*224);
  size_t qrW16   = alloc(1024u*288);
  size_t crW16   = alloc(1024u*544);
  size_t ctxR16  = alloc(65536);            // recurrent Wh fp16 (same layout)
  size_t qrR16   = alloc(65536);
  size_t crR16   = alloc(65536);
  size_t c_xg    = alloc((size_t)RU*1024);  // rows 25600.. = q_xg; reused attn fp16 + cr_xg
  size_t q_enc   = alloc(1000u*256);
  size_t D_enc   = alloc(25600u*256);
  size_t gate_q  = alloc(1000);
  size_t gate_c  = alloc(25600);
  size_t M_qc    = alloc(2560000);
  size_t an_     = alloc(2560000);          // an fp16 hi/lo overlay
  size_t bn_     = alloc(3276800);          // bnT fp16 hi/lo [100][256][128]
  size_t featc   = alloc(20000);
  size_t featr   = alloc(51200);
  size_t RnQ     = alloc(2560000);
  size_t Xb      = alloc(10u*2560*512);
  size_t Sbuf    = alloc(6553600);          // D16t overlay pre-attention
  size_t RmD     = alloc(10u*2560*512);     // D16 overlay pre-attention; PV out
  size_t rnq16   = alloc(10000u*288);
  size_t qr_xg   = alloc(10000u*1024);      // S fp16 slab pool during attention...
  size_t q_hs    = alloc(100u*100*256);     // ...contiguous: qr_xg,q_hs,rmd16,c_hs
  size_t rmd16   = alloc(25600u*544);
  size_t c_hs    = alloc(100u*256*256);
  size_t q_out   = alloc(100u*256);
  size_t c_out   = alloc(100u*256);

  if (ws_size < o*sizeof(float)) {
    k_sentinel<<<1,64,0,stream>>>(out, out_size);
    return;
  }

  // fp16 views
  _Float16* cvh = (_Float16*)(w + cv16);       _Float16* cvl = cvh + RU*224;
  _Float16* cWh = (_Float16*)(w + ctxW16);     _Float16* cWl = cWh + 1024L*224;
  _Float16* qWh = (_Float16*)(w + qrW16);      _Float16* qWl = qWh + 1024L*288;
  _Float16* rWh = (_Float16*)(w + crW16);      _Float16* rWl = rWh + 1024L*544;
  _Float16* cR16 = (_Float16*)(w + ctxR16);
  _Float16* qR16 = (_Float16*)(w + qrR16);
  _Float16* rR16 = (_Float16*)(w + crR16);
  _Float16* nqh = (_Float16*)(w + rnq16);      _Float16* nql = nqh + 10000L*288;
  _Float16* mdh = (_Float16*)(w + rmd16);      _Float16* mdl = mdh + 25600L*544;
  // attention overlays (dead-region reuse)
  _Float16* Xh  = (_Float16*)(w + c_xg);       // 4 x 13,107,200 halves <= c_xg
  _Float16* Xl  = Xh  + 13107200L;
  _Float16* Xth = Xl  + 13107200L;
  _Float16* Xtl = Xth + 13107200L;
  // S fp16 slab pool (5 b's at a time): contiguous dead run qr_xg..c_hs
  _Float16* ShA = (_Float16*)(w + qr_xg);
  _Float16* SlA = ShA + 5L*6553600L;
  // pre-attention fp16 overlays
  _Float16* anh = (_Float16*)(w + an_);        _Float16* anl = anh + 2560000L;
  _Float16* bth = (_Float16*)(w + bn_);        _Float16* btl = bth + 3276800L;
  _Float16* D16h = (_Float16*)(w + RmD);       _Float16* D16l = D16h + 6553600L;   // row-major
  _Float16* Dt16h = (_Float16*)(w + Sbuf);     _Float16* Dt16l = Dt16h + 6553600L; // transposed
  _Float16* q16h = (_Float16*)(w + q_hs);      _Float16* q16l = q16h + 256000L;
  _Float16* qt16h = q16l + 256000L;            _Float16* qt16l = qt16h + 327680L;  // [b][256][128]
  float* q_xg_p = w + c_xg + 25600L*1024;

  // --- weight transforms + unified embeddings ---
  k_wsplit<<<1024,256,0,stream>>>(ctx_Wi, cWh, cWl, 200, 224);
  k_wsplit<<<1024,256,0,stream>>>(qr_Wi,  qWh, qWl, 258, 288);
  k_wsplit<<<1024,256,0,stream>>>(cr_Wi,  rWh, rWl, 514, 544);
  k_cvt16<<<cdiv(131072,256),256,0,stream>>>(ctx_Wh, cR16, 131072);
  k_cvt16<<<cdiv(131072,256),256,0,stream>>>(qr_Wh,  qR16, 131072);
  k_cvt16<<<cdiv(131072,256),256,0,stream>>>(cr_Wh,  rR16, 131072);
  k_embed16u<<<(int)RU, 256, 0, stream>>>(contents, qa, ef, ed, cvh, cvl, 224);

  // --- ctx input projection (content + question, one dispatch) ---
  k_mfma<<<dim3(208,8,1),256,0,stream>>>(cvh, cvl, cWh, cWl, w+c_xg,
      (int)RU, 224, 1024, 1024, 0L,0L,0L, 1,1, 3, nullptr, nullptr, 0L);

  // --- ctx LSTMs (content T=256 + question T=100, one dispatch) ---
  k_lstm2<<<dim3(110,2),512,0,stream>>>(
      w+c_xg, cR16, ctx_b, w+D_enc, 100, 256, 1024,
      q_xg_p, cR16, ctx_b, w+q_enc, 100, 1024);

  // --- reasoning gates ---
  k_gate<<<cdiv(1000,4),256,0,stream>>>(w+q_enc, grW, grB, w+gate_q, 1000);
  k_gate<<<cdiv(25600,4),256,0,stream>>>(w+D_enc, grW, grB, w+gate_c, 25600);

  // --- fp16 operand prep for matching GEMMs ---
  k_split_hl<<<cdiv(6553600,256),256,0,stream>>>(w+D_enc, D16h, D16l, 6553600L);
  k_split_hl<<<cdiv(256000,256),256,0,stream>>>(w+q_enc, q16h, q16l, 256000L);
  k_transp_hl<<<dim3(8,8,100),256,0,stream>>>(w+D_enc, Dt16h, Dt16l, 256, 256, 65536L, 65536L);
  k_transp_hl<<<dim3(4,8,10),256,0,stream>>>(w+q_enc, qt16h, qt16l, 100, 128, 25600L, 32768L);

  // --- M_qc[bn] = q_enc[b] @ D_enc[bn]^T  (MFMA, z=100) ---
  k_mfma<<<dim3(1,2,100),256,0,stream>>>(q16h, q16l, D16h, D16l, w+M_qc,
      100, 256, 256, 256, 25600L, 65536L, 25600L, 10, 1, 3, nullptr, nullptr, 0L);

  // --- softmaxes + feats (emit fp16 splits directly) ---
  k_an_feat16<<<10000,256,0,stream>>>(w+M_qc, anh, anl, w+featc);
  k_bn_feat16<<<100,1024,0,stream>>>(w+M_qc, bth, btl, w+featr);

  // --- RnQ = an @ D_enc ---
  k_mfma<<<dim3(1,2,100),256,0,stream>>>(anh, anl, Dt16h, Dt16l, w+RnQ,
      100, 256, 256, 256, 25600L, 65536L, 25600L, 1, 1, 3, nullptr, nullptr, 0L);

  // --- RnD = bn^T @ q_enc -> X[...,256:512] ---
  k_mfma<<<dim3(2,2,100),256,0,stream>>>(bth, btl, qt16h, qt16l, w+Xb+256,
      256, 128, 256, 512, 32768L, 32768L, 131072L, 1, 10, 3, nullptr, nullptr, 0L);

  // --- X[...,0:256] = D_enc ---
  k_copy_to_x<<<25600,256,0,stream>>>(w+D_enc, w+Xb);

  // --- fp16 splits of X (row-major and transposed) ---
  k_split_hl<<<51200,256,0,stream>>>(w+Xb, Xh, Xl, 13107200L);
  k_transpose_hl<<<dim3(80,16,10),256,0,stream>>>(w+Xb, Xth, Xtl);

  // --- cross-doc attention, 5 b's per macro-iteration, fp16-S pipeline ---
  for (int half = 0; half < 2; ++half) {
    const long xo = (long)half*5*1310720;
    k_mfma<<<dim3(20,20,5),256,0,stream>>>(Xh+xo, Xl+xo, Xh+xo, Xl+xo, nullptr,
        2560, 512, 2560, 2560, 1310720L, 1310720L, 0L, 1, 1, 2, ShA, SlA, 6553600L);
    k_softmax2560_io16<<<dim3(2560,5),256,0,stream>>>(ShA, SlA, 6553600L);
    k_mfma<<<dim3(20,4,5),256,0,stream>>>(ShA, SlA, Xth+xo, Xtl+xo, w+RmD+xo,
        2560, 2560, 512, 512, 6553600L, 1310720L, 1310720L, 1, 1, 2,
        nullptr, nullptr, 0L);
  }

  // --- qr + cr input builds and projections ---
  k_build_rnq16<<<10000,320,0,stream>>>(w+RnQ, w+featc, w+gate_q, nqh, nql);
  k_mfma<<<dim3(79,8,1),256,0,stream>>>(nqh, nql, qWh, qWl, w+qr_xg,
      10000, 288, 1024, 1024, 0L,0L,0L, 1,1, 3, nullptr, nullptr, 0L);
  k_build_rmd16<<<25600,256,0,stream>>>(w+RmD, w+featr, w+gate_c, mdh, mdl);
  k_mfma<<<dim3(200,8,1),256,0,stream>>>(mdh, mdl, rWh, rWl, w+c_xg,
      25600, 544, 1024, 1024, 0L,0L,0L, 1,1, 3, nullptr, nullptr, 0L);

  // --- qr + cr LSTMs in one dispatch ---
  k_lstm2<<<dim3(200,2),512,0,stream>>>(
      w+c_xg, rR16, cr_b, w+c_hs, 100, 256, 1024,
      w+qr_xg, qR16, qr_b, w+q_hs, 100, 1024);

  // --- max over time ---
  k_maxt2<<<200,256,0,stream>>>(w+c_hs, w+c_out, 100, 256, w+q_hs, w+q_out, 100);

  // --- decode head ---
  k_final<<<10,512,0,stream>>>(w+q_out, w+c_out, gnW, gnB, decW, decB, logics, out);
}